// Round 2
// baseline (3673.981 us; speedup 1.0000x reference)
//
#include <hip/hip_runtime.h>
#include <cmath>

#define THREADS 256

static constexpr int N_NODES   = 100000;
static constexpr int N_EDGES   = 800000;
static constexpr int NIN       = 40000;   // input_mask: n < NIN
static constexpr int NOUT_BASE = 60000;   // output_mask: n >= NOUT_BASE
static constexpr int NOUT      = 40000;

// ---- workspace layout (32-bit words) ----
static constexpr size_t OFF_NFI   = 0;                                // 40000*128 f32
static constexpr size_t OFF_F1    = OFF_NFI  + (size_t)NIN  * 128;    // 40000*32  f32
static constexpr size_t OFF_F2    = OFF_F1   + (size_t)NOUT * 32;     // 40000*32  u32 (keys)
static constexpr size_t OFF_CNT   = OFF_F2   + (size_t)NOUT * 32;     // 40000 u32
static constexpr size_t OFF_CTRO  = OFF_CNT  + NOUT;                  // 1 u32
static constexpr size_t OFF_CTRI  = OFF_CTRO + 1;                     // 1 u32
static constexpr size_t OFF_LISTO = OFF_CTRI + 1;                     // E u32
static constexpr size_t OFF_LISTI = OFF_LISTO + N_EDGES;              // E u32

__device__ __forceinline__ float lrelu(float x) { return x > 0.0f ? x : 0.2f * x; }

// monotonic float->uint key for atomicMax-based segment max
__device__ __forceinline__ unsigned fkey(float f) {
    unsigned u = __float_as_uint(f);
    return (u & 0x80000000u) ? ~u : (u | 0x80000000u);
}
__device__ __forceinline__ float funkey(unsigned k) {
    return (k & 0x80000000u) ? __uint_as_float(k & 0x7fffffffu) : __uint_as_float(~k);
}

// Generic dense layer on LDS activations.
// 64 rows per block; thread t handles row (t&63), output neurons [grp*O/4, grp*O/4 + O/4).
template<int K, int O, int SIN, int SOUT, bool RELU>
__device__ __forceinline__ void layer_lds(const float* __restrict__ W, const float* __restrict__ Bv,
                                          const float* __restrict__ xin, float* __restrict__ xout) {
    const int tid  = threadIdx.x;
    const int lane = tid & 63;
    const int grp  = __builtin_amdgcn_readfirstlane(tid >> 6);
    constexpr int NJ = O / 4;
    const int nb = grp * NJ;
    float acc[NJ];
#pragma unroll
    for (int j = 0; j < NJ; ++j) acc[j] = Bv[nb + j];
    const float* xr = xin + lane * SIN;
#pragma unroll 4
    for (int k = 0; k < K; ++k) {
        const float xv = xr[k];
        const float* wr = W + k * O + nb;
#pragma unroll
        for (int j = 0; j < NJ; ++j) acc[j] = fmaf(xv, wr[j], acc[j]);
    }
    __syncthreads();   // all reads of xin done before anyone overwrites regions
    float* orow = xout + lane * SOUT + nb;
#pragma unroll
    for (int j = 0; j < NJ; ++j) orow[j] = RELU ? lrelu(acc[j]) : acc[j];
    __syncthreads();
}

// ---- edge compaction: keep only edges whose scatter target survives the output mask ----
__global__ __launch_bounds__(THREADS)
void compact_k(const int* __restrict__ dst_out, const int* __restrict__ dst_in,
               unsigned* __restrict__ ctro, unsigned* __restrict__ ctri,
               unsigned* __restrict__ listo, unsigned* __restrict__ listi) {
    const int e = blockIdx.x * THREADS + threadIdx.x;
    if (e >= N_EDGES) return;
    if (dst_out[e] < NIN)        { unsigned p = atomicAdd(ctro, 1u); listo[p] = (unsigned)e; }
    if (dst_in[e] >= NOUT_BASE)  { unsigned p = atomicAdd(ctri, 1u); listi[p] = (unsigned)e; }
}

// ---- o2i edge MLP (144->64->64->64->64->128) + atomic scatter-add into nfi ----
__global__ __launch_bounds__(THREADS)
void edge_out_mlp(const float* __restrict__ nf, const float* __restrict__ ef,
                  const int* __restrict__ src, const int* __restrict__ dst,
                  const unsigned* __restrict__ list, const unsigned* __restrict__ counter,
                  const float* __restrict__ w0, const float* __restrict__ b0,
                  const float* __restrict__ w1, const float* __restrict__ b1,
                  const float* __restrict__ w2, const float* __restrict__ b2,
                  const float* __restrict__ w3, const float* __restrict__ b3,
                  const float* __restrict__ w4, const float* __restrict__ b4,
                  float* __restrict__ nfi) {
    __shared__ float A[64 * 148];
    __shared__ float Bb[64 * 65];
    __shared__ int s_eid[64], s_src[64], s_dst[64];
    const unsigned total = *counter;
    const unsigned base  = (unsigned)blockIdx.x * 64u;
    if (base >= total) return;
    const int tid = threadIdx.x;
    if (tid < 64) {
        const unsigned idx = base + (unsigned)tid;
        const int e = (idx < total) ? (int)list[idx] : -1;
        s_eid[tid] = e;
        s_src[tid] = (e >= 0) ? src[e] : 0;
        s_dst[tid] = (e >= 0) ? dst[e] : 0;
    }
    __syncthreads();
    // stage x = [nf[src] | nf[dst] | ef] : 144 floats = 36 float4 per edge
    for (int i = tid; i < 64 * 36; i += THREADS) {
        const int el = i / 36, q = i % 36;
        float4 v = make_float4(0.f, 0.f, 0.f, 0.f);
        if (s_eid[el] >= 0) {
            if (q < 16)      v = ((const float4*)(nf + (size_t)s_src[el] * 64))[q];
            else if (q < 32) v = ((const float4*)(nf + (size_t)s_dst[el] * 64))[q - 16];
            else             v = ((const float4*)(ef + (size_t)s_eid[el] * 16))[q - 32];
        }
        *(float4*)(A + el * 148 + q * 4) = v;
    }
    __syncthreads();
    layer_lds<144, 64, 148, 65, true>(w0, b0, A, Bb);
    layer_lds< 64, 64,  65, 65, true>(w1, b1, Bb, A);
    layer_lds< 64, 64,  65, 65, true>(w2, b2, A, Bb);
    layer_lds< 64, 64,  65, 65, true>(w3, b3, Bb, A);
    // final 64 -> 128, no activation, straight to atomic scatter
    const int lane = tid & 63;
    const int grp  = __builtin_amdgcn_readfirstlane(tid >> 6);
    float acc[32];
#pragma unroll
    for (int j = 0; j < 32; ++j) acc[j] = b4[grp * 32 + j];
    const float* xr = A + lane * 65;
#pragma unroll 4
    for (int k = 0; k < 64; ++k) {
        const float xv = xr[k];
        const float* wr = w4 + k * 128 + grp * 32;
#pragma unroll
        for (int j = 0; j < 32; ++j) acc[j] = fmaf(xv, wr[j], acc[j]);
    }
    if (s_eid[lane] >= 0) {
        float* p = nfi + (size_t)s_dst[lane] * 128 + grp * 32;
#pragma unroll
        for (int j = 0; j < 32; ++j) atomicAdd(p + j, acc[j]);
    }
}

// ---- i2o edge MLP (144->64->64->64->65) + gate + mean/max scatter ----
__global__ __launch_bounds__(THREADS)
void edge_in_mlp(const float* __restrict__ nf, const float* __restrict__ ef,
                 const int* __restrict__ src, const int* __restrict__ dst,
                 const unsigned* __restrict__ list, const unsigned* __restrict__ counter,
                 const float* __restrict__ w0, const float* __restrict__ b0,
                 const float* __restrict__ w1, const float* __restrict__ b1,
                 const float* __restrict__ w2, const float* __restrict__ b2,
                 const float* __restrict__ w3, const float* __restrict__ b3,
                 float* __restrict__ f1sum, unsigned* __restrict__ f2key, unsigned* __restrict__ cnt) {
    __shared__ float A[64 * 148];
    __shared__ float Bb[64 * 65];
    __shared__ int s_eid[64], s_src[64], s_dst[64];
    const unsigned total = *counter;
    const unsigned base  = (unsigned)blockIdx.x * 64u;
    if (base >= total) return;
    const int tid = threadIdx.x;
    if (tid < 64) {
        const unsigned idx = base + (unsigned)tid;
        const int e = (idx < total) ? (int)list[idx] : -1;
        s_eid[tid] = e;
        s_src[tid] = (e >= 0) ? src[e] : 0;
        s_dst[tid] = (e >= 0) ? dst[e] : 0;
    }
    __syncthreads();
    for (int i = tid; i < 64 * 36; i += THREADS) {
        const int el = i / 36, q = i % 36;
        float4 v = make_float4(0.f, 0.f, 0.f, 0.f);
        if (s_eid[el] >= 0) {
            if (q < 16)      v = ((const float4*)(nf + (size_t)s_src[el] * 64))[q];
            else if (q < 32) v = ((const float4*)(nf + (size_t)s_dst[el] * 64))[q - 16];
            else             v = ((const float4*)(ef + (size_t)s_eid[el] * 16))[q - 32];
        }
        *(float4*)(A + el * 148 + q * 4) = v;
    }
    __syncthreads();
    layer_lds<144, 64, 148, 65, true>(w0, b0, A, Bb);
    layer_lds< 64, 64,  65, 65, true>(w1, b1, Bb, A);
    layer_lds< 64, 64,  65, 65, true>(w2, b2, A, Bb);
    // final 64 -> 65 (no activation) into A at stride 67
    const int lane = tid & 63;
    const int grp  = __builtin_amdgcn_readfirstlane(tid >> 6);
    {
        const int nb = grp * 16;                 // groups cover 0..63; grp3 also does n=64
        float acc[17];
#pragma unroll
        for (int j = 0; j < 17; ++j) acc[j] = b3[nb + j];   // nb+16 <= 64: in-bounds
        const float* xr = Bb + lane * 65;
#pragma unroll 4
        for (int k = 0; k < 64; ++k) {
            const float xv = xr[k];
            const float* wr = w3 + k * 65 + nb;
#pragma unroll
            for (int j = 0; j < 17; ++j) acc[j] = fmaf(xv, wr[j], acc[j]);
        }
        __syncthreads();
        float* orow = A + lane * 67 + nb;        // overlapping n=16/32/48 written twice w/ identical values
#pragma unroll
        for (int j = 0; j < 17; ++j) orow[j] = acc[j];
        __syncthreads();
    }
    // gate + scatter: thread handles row=lane, gated columns [grp*16, grp*16+16)
    if (s_eid[lane] >= 0) {
        const float m0 = A[lane * 67 + 0];
        const float kg = 1.0f / (1.0f + expf(-m0));
        const int r = s_dst[lane] - NOUT_BASE;
#pragma unroll
        for (int j = 0; j < 16; ++j) {
            const int c = grp * 16 + j;          // c<32 <=> grp<2 : wave-uniform branch
            const float v = A[lane * 67 + 1 + c] * kg;
            if (c < 32) atomicAdd(f1sum + (size_t)r * 32 + c, v);
            else        atomicMax(f2key + (size_t)r * 32 + (c - 32), fkey(v));
        }
        if (tid < 64) atomicAdd(cnt + r, 1u);
    }
}

// ---- ri node MLP (192->64->64->64->64) for nodes [0, NIN) ----
__global__ __launch_bounds__(THREADS)
void node_ri(const float* __restrict__ nf, const float* __restrict__ nfi,
             const float* __restrict__ w0, const float* __restrict__ b0,
             const float* __restrict__ w1, const float* __restrict__ b1,
             const float* __restrict__ w2, const float* __restrict__ b2,
             const float* __restrict__ w3, const float* __restrict__ b3,
             float* __restrict__ out) {
    __shared__ float XA[64 * 68];    // nf part (stride 68), reused as h (stride 65)
    __shared__ float XB[64 * 132];   // nfi part (stride 132), reused as h (stride 65)
    const int tid  = threadIdx.x;
    const int base = blockIdx.x * 64;
    for (int i = tid; i < 64 * 16; i += THREADS) {
        const int nl = i / 16, q = i % 16;
        *(float4*)(XA + nl * 68 + q * 4) = ((const float4*)(nf + (size_t)(base + nl) * 64))[q];
    }
    for (int i = tid; i < 64 * 32; i += THREADS) {
        const int nl = i / 32, q = i % 32;
        *(float4*)(XB + nl * 132 + q * 4) = ((const float4*)(nfi + (size_t)(base + nl) * 128))[q];
    }
    __syncthreads();
    const int lane = tid & 63;
    const int grp  = __builtin_amdgcn_readfirstlane(tid >> 6);
    {   // L0: 192 -> 64 (reads XA 64 + XB 128), writes h into XA @65
        const int nb = grp * 16;
        float acc[16];
#pragma unroll
        for (int j = 0; j < 16; ++j) acc[j] = b0[nb + j];
        const float* xa = XA + lane * 68;
#pragma unroll 4
        for (int k = 0; k < 64; ++k) {
            const float xv = xa[k];
            const float* wr = w0 + k * 64 + nb;
#pragma unroll
            for (int j = 0; j < 16; ++j) acc[j] = fmaf(xv, wr[j], acc[j]);
        }
        const float* xb = XB + lane * 132;
#pragma unroll 4
        for (int k = 0; k < 128; ++k) {
            const float xv = xb[k];
            const float* wr = w0 + (64 + k) * 64 + nb;
#pragma unroll
            for (int j = 0; j < 16; ++j) acc[j] = fmaf(xv, wr[j], acc[j]);
        }
        __syncthreads();
        float* orow = XA + lane * 65 + nb;
#pragma unroll
        for (int j = 0; j < 16; ++j) orow[j] = lrelu(acc[j]);
        __syncthreads();
    }
    layer_lds<64, 64, 65, 65, true>(w1, b1, XA, XB);
    layer_lds<64, 64, 65, 65, true>(w2, b2, XB, XA);
    {   // final 64 -> 64 -> out
        const int nb = grp * 16;
        float acc[16];
#pragma unroll
        for (int j = 0; j < 16; ++j) acc[j] = b3[nb + j];
        const float* xr = XA + lane * 65;
#pragma unroll 4
        for (int k = 0; k < 64; ++k) {
            const float xv = xr[k];
            const float* wr = w3 + k * 64 + nb;
#pragma unroll
            for (int j = 0; j < 16; ++j) acc[j] = fmaf(xv, wr[j], acc[j]);
        }
        float* op = out + (size_t)(base + lane) * 64 + nb;
#pragma unroll
        for (int j = 0; j < 16; ++j) op[j] = acc[j];
    }
}

// ---- ro node MLP (128->64->64->64->64) for nodes [NOUT_BASE, N) ----
__global__ __launch_bounds__(THREADS)
void node_ro(const float* __restrict__ nf, const float* __restrict__ f1sum,
             const unsigned* __restrict__ f2key, const unsigned* __restrict__ cnt,
             const float* __restrict__ w0, const float* __restrict__ b0,
             const float* __restrict__ w1, const float* __restrict__ b1,
             const float* __restrict__ w2, const float* __restrict__ b2,
             const float* __restrict__ w3, const float* __restrict__ b3,
             float* __restrict__ out) {
    __shared__ float A[64 * 132];
    __shared__ float Bb[64 * 65];
    const int tid  = threadIdx.x;
    const int base = NOUT_BASE + blockIdx.x * 64;
    for (int i = tid; i < 64 * 128; i += THREADS) {
        const int nl = i / 128, c = i % 128;
        const int n = base + nl;
        const int r = n - NOUT_BASE;
        float v;
        if (c < 64) v = nf[(size_t)n * 64 + c];
        else {
            const unsigned cc = cnt[r];
            if (c < 96) v = f1sum[(size_t)r * 32 + (c - 64)] / fmaxf((float)cc, 1.0f);
            else        v = (cc > 0u) ? funkey(f2key[(size_t)r * 32 + (c - 96)]) : 0.0f;
        }
        A[nl * 132 + c] = v;
    }
    __syncthreads();
    const int lane = tid & 63;
    const int grp  = __builtin_amdgcn_readfirstlane(tid >> 6);
    layer_lds<128, 64, 132, 65, true>(w0, b0, A, Bb);
    layer_lds< 64, 64,  65, 65, true>(w1, b1, Bb, A);
    layer_lds< 64, 64,  65, 65, true>(w2, b2, A, Bb);
    {   // final 64 -> 64 -> out
        const int nb = grp * 16;
        float acc[16];
#pragma unroll
        for (int j = 0; j < 16; ++j) acc[j] = b3[nb + j];
        const float* xr = Bb + lane * 65;
#pragma unroll 4
        for (int k = 0; k < 64; ++k) {
            const float xv = xr[k];
            const float* wr = w3 + k * 64 + nb;
#pragma unroll
            for (int j = 0; j < 16; ++j) acc[j] = fmaf(xv, wr[j], acc[j]);
        }
        float* op = out + (size_t)(base + lane) * 64 + nb;
#pragma unroll
        for (int j = 0; j < 16; ++j) op[j] = acc[j];
    }
}

extern "C" void kernel_launch(void* const* d_in, const int* in_sizes, int n_in,
                              void* d_out, int out_size, void* d_ws, size_t ws_size,
                              hipStream_t stream) {
    const float* nf     = (const float*)d_in[0];
    const float* ef_out = (const float*)d_in[1];
    const float* ef_in  = (const float*)d_in[2];
    const float* o2i_w0 = (const float*)d_in[3];  const float* o2i_b0 = (const float*)d_in[4];
    const float* o2i_w1 = (const float*)d_in[5];  const float* o2i_b1 = (const float*)d_in[6];
    const float* o2i_w2 = (const float*)d_in[7];  const float* o2i_b2 = (const float*)d_in[8];
    const float* o2i_w3 = (const float*)d_in[9];  const float* o2i_b3 = (const float*)d_in[10];
    const float* o2i_w4 = (const float*)d_in[11]; const float* o2i_b4 = (const float*)d_in[12];
    const float* i2o_w0 = (const float*)d_in[13]; const float* i2o_b0 = (const float*)d_in[14];
    const float* i2o_w1 = (const float*)d_in[15]; const float* i2o_b1 = (const float*)d_in[16];
    const float* i2o_w2 = (const float*)d_in[17]; const float* i2o_b2 = (const float*)d_in[18];
    const float* i2o_w3 = (const float*)d_in[19]; const float* i2o_b3 = (const float*)d_in[20];
    const float* ri_w0  = (const float*)d_in[21]; const float* ri_b0  = (const float*)d_in[22];
    const float* ri_w1  = (const float*)d_in[23]; const float* ri_b1  = (const float*)d_in[24];
    const float* ri_w2  = (const float*)d_in[25]; const float* ri_b2  = (const float*)d_in[26];
    const float* ri_w3  = (const float*)d_in[27]; const float* ri_b3  = (const float*)d_in[28];
    const float* ro_w0  = (const float*)d_in[29]; const float* ro_b0  = (const float*)d_in[30];
    const float* ro_w1  = (const float*)d_in[31]; const float* ro_b1  = (const float*)d_in[32];
    const float* ro_w2  = (const float*)d_in[33]; const float* ro_b2  = (const float*)d_in[34];
    const float* ro_w3  = (const float*)d_in[35]; const float* ro_b3  = (const float*)d_in[36];
    const int* src_out  = (const int*)d_in[37];
    const int* dst_out  = (const int*)d_in[38];
    const int* src_in   = (const int*)d_in[39];
    const int* dst_in   = (const int*)d_in[40];

    unsigned* ws   = (unsigned*)d_ws;
    float*    nfi  = (float*)(ws + OFF_NFI);
    float*    f1s  = (float*)(ws + OFF_F1);
    unsigned* f2k  = ws + OFF_F2;
    unsigned* cnt  = ws + OFF_CNT;
    unsigned* ctro = ws + OFF_CTRO;
    unsigned* ctri = ws + OFF_CTRI;
    unsigned* lsto = ws + OFF_LISTO;
    unsigned* lsti = ws + OFF_LISTI;

    // zero accumulators + counters (f2 keys: 0 is below every real key)
    hipMemsetAsync(d_ws, 0, OFF_LISTO * sizeof(unsigned), stream);
    // zero the masked-out middle band of the output
    hipMemsetAsync((char*)d_out + (size_t)NIN * 64 * sizeof(float), 0,
                   (size_t)(NOUT_BASE - NIN) * 64 * sizeof(float), stream);

    compact_k<<<(N_EDGES + THREADS - 1) / THREADS, THREADS, 0, stream>>>(
        dst_out, dst_in, ctro, ctri, lsto, lsti);

    edge_out_mlp<<<N_EDGES / 64, THREADS, 0, stream>>>(
        nf, ef_out, src_out, dst_out, lsto, ctro,
        o2i_w0, o2i_b0, o2i_w1, o2i_b1, o2i_w2, o2i_b2, o2i_w3, o2i_b3, o2i_w4, o2i_b4, nfi);

    edge_in_mlp<<<N_EDGES / 64, THREADS, 0, stream>>>(
        nf, ef_in, src_in, dst_in, lsti, ctri,
        i2o_w0, i2o_b0, i2o_w1, i2o_b1, i2o_w2, i2o_b2, i2o_w3, i2o_b3, f1s, f2k, cnt);

    node_ri<<<NIN / 64, THREADS, 0, stream>>>(
        nf, nfi, ri_w0, ri_b0, ri_w1, ri_b1, ri_w2, ri_b2, ri_w3, ri_b3, (float*)d_out);

    node_ro<<<NOUT / 64, THREADS, 0, stream>>>(
        nf, f1s, f2k, cnt, ro_w0, ro_b0, ro_w1, ro_b1, ro_w2, ro_b2, ro_w3, ro_b3, (float*)d_out);
}

// Round 3
// 715.999 us; speedup vs baseline: 5.1313x; 5.1313x over previous
//
#include <hip/hip_runtime.h>
#include <cmath>

#define THREADS 256

static constexpr int N_NODES   = 100000;
static constexpr int N_EDGES   = 800000;
static constexpr int NIN       = 40000;   // input_mask: n < NIN
static constexpr int NOUT_BASE = 60000;   // output_mask: n >= NOUT_BASE
static constexpr int NOUT      = 40000;

// ---- workspace layout (32-bit words) ----
static constexpr size_t OFF_NFI   = 0;                                // 40000*128 f32
static constexpr size_t OFF_F1    = OFF_NFI  + (size_t)NIN  * 128;    // 40000*32  f32
static constexpr size_t OFF_F2    = OFF_F1   + (size_t)NOUT * 32;     // 40000*32  u32 (keys)
static constexpr size_t OFF_CNT   = OFF_F2   + (size_t)NOUT * 32;     // 40000 u32
static constexpr size_t OFF_CTRO  = OFF_CNT  + NOUT;                  // 1 u32
static constexpr size_t OFF_CTRI  = OFF_CTRO + 1;                     // 1 u32
static constexpr size_t OFF_LISTO = OFF_CTRI + 1;                     // E u32
static constexpr size_t OFF_LISTI = OFF_LISTO + N_EDGES;              // E u32
static constexpr size_t OFF_WB    = OFF_LISTI + N_EDGES;              // bf16 weights region

// converted-weight offsets (ushort units). [n][k] layout, strides = Kp+8 (bank pad)
static constexpr unsigned OW_O2I0 = 0;       // 64 x 168
static constexpr unsigned OW_O2I1 = 10752;   // 64 x 72
static constexpr unsigned OW_O2I2 = 15360;
static constexpr unsigned OW_O2I3 = 19968;
static constexpr unsigned OW_O2I4 = 24576;   // 128 x 72
static constexpr unsigned OW_I2O0 = 33792;   // 64 x 168
static constexpr unsigned OW_I2O1 = 44544;
static constexpr unsigned OW_I2O2 = 49152;
static constexpr unsigned OW_I2O3 = 53760;   // 80 x 72 (N=65 padded)
static constexpr unsigned OW_RI0  = 59520;   // 64 x 200
static constexpr unsigned OW_RI1  = 72320;
static constexpr unsigned OW_RI2  = 76928;
static constexpr unsigned OW_RI3  = 81536;
static constexpr unsigned OW_RO0  = 86144;   // 64 x 136
static constexpr unsigned OW_RO1  = 94848;
static constexpr unsigned OW_RO2  = 99456;
static constexpr unsigned OW_RO3  = 104064;  // end 108672

typedef __attribute__((ext_vector_type(8))) short short8;
typedef __attribute__((ext_vector_type(4))) float f32x4;

__device__ __forceinline__ float lrelu(float x) { return x > 0.0f ? x : 0.2f * x; }

__device__ __forceinline__ unsigned short f2b(float f) {   // RNE f32->bf16
    unsigned u = __float_as_uint(f);
    return (unsigned short)((u + 0x7fffu + ((u >> 16) & 1u)) >> 16);
}
__device__ __forceinline__ unsigned fkey(float f) {
    unsigned u = __float_as_uint(f);
    return (u & 0x80000000u) ? ~u : (u | 0x80000000u);
}
__device__ __forceinline__ float funkey(unsigned k) {
    return (k & 0x80000000u) ? __uint_as_float(k & 0x7fffffffu) : __uint_as_float(~k);
}

// copy n ushorts (n % 8 == 0, 16B aligned) global -> LDS
__device__ __forceinline__ void stage_w(unsigned short* dst, const unsigned short* src, int n, int tid) {
    for (int i = tid * 8; i < n; i += THREADS * 8)
        *(uint4*)(dst + i) = *(const uint4*)(src + i);
}

// One dense layer tile: MT m-tiles (16 rows each) per wave, NT n-tiles, KT k-steps of 32.
// X: bf16 LDS activations [rows][XSTR]; W: bf16 LDS weights [n][WSTR] (pre-transposed).
// A-frag: m=lane&15, k=(lane>>4)*8+j ; B-frag: n=lane&15, same k ; D: col=lane&15, row=(lane>>4)*4+reg.
template<int MT, int NT, int KT, int XSTR, int WSTR>
__device__ __forceinline__ void gemm_core(const unsigned short* X, const unsigned short* W,
                                          const float* bias, int biasN, int wv, int lane,
                                          f32x4 (&acc)[MT][NT]) {
    const int r = lane & 15, kg = lane >> 4;
    short8 a[MT][KT];
#pragma unroll
    for (int mt = 0; mt < MT; ++mt)
#pragma unroll
        for (int kk = 0; kk < KT; ++kk)
            a[mt][kk] = *(const short8*)(X + (wv * 16 * MT + mt * 16 + r) * XSTR + kk * 32 + kg * 8);
#pragma unroll
    for (int nt = 0; nt < NT; ++nt) {
        const int c = nt * 16 + r;
        const float bv = (c < biasN) ? bias[c] : 0.0f;
#pragma unroll
        for (int mt = 0; mt < MT; ++mt) acc[mt][nt] = (f32x4){bv, bv, bv, bv};
    }
#pragma unroll
    for (int kk = 0; kk < KT; ++kk)
#pragma unroll
        for (int nt = 0; nt < NT; ++nt) {
            short8 b = *(const short8*)(W + (nt * 16 + r) * WSTR + kk * 32 + kg * 8);
#pragma unroll
            for (int mt = 0; mt < MT; ++mt)
                acc[mt][nt] = __builtin_amdgcn_mfma_f32_16x16x32_bf16(a[mt][kk], b, acc[mt][nt], 0, 0, 0);
        }
}

// leaky-relu + bf16 + in-place writeback to X (each wave touches only its own rows)
template<int MT, int NT, int XSTR>
__device__ __forceinline__ void writeback(unsigned short* X, f32x4 (&acc)[MT][NT], int wv, int lane) {
    const int r = lane & 15, kg = lane >> 4;
#pragma unroll
    for (int mt = 0; mt < MT; ++mt)
#pragma unroll
        for (int nt = 0; nt < NT; ++nt)
#pragma unroll
            for (int q = 0; q < 4; ++q)
                X[(wv * 16 * MT + mt * 16 + kg * 4 + q) * XSTR + nt * 16 + r] = f2b(lrelu(acc[mt][nt][q]));
}

// ---- weight conversion: f32 [K][N] -> bf16 [Np][stride] transposed, zero-padded ----
struct WDesc { const float* w; int K, N, stride, Np; unsigned off; };
struct WTab { WDesc d[17]; };

__global__ __launch_bounds__(THREADS)
void convert_w(WTab t, unsigned short* wts) {
    const WDesc d = t.d[blockIdx.y];
    const int idx = blockIdx.x * THREADS + threadIdx.x;
    const int tot = d.Np * d.stride;
    if (idx >= tot) return;
    const int n = idx / d.stride, k = idx - n * d.stride;
    const float v = (k < d.K && n < d.N) ? d.w[(size_t)k * d.N + n] : 0.0f;
    wts[d.off + idx] = f2b(v);
}

// ---- edge compaction ----
__global__ __launch_bounds__(THREADS)
void compact_k(const int* __restrict__ dst_out, const int* __restrict__ dst_in,
               unsigned* __restrict__ ctro, unsigned* __restrict__ ctri,
               unsigned* __restrict__ listo, unsigned* __restrict__ listi) {
    const int e = blockIdx.x * THREADS + threadIdx.x;
    if (e >= N_EDGES) return;
    if (dst_out[e] < NIN)        { unsigned p = atomicAdd(ctro, 1u); listo[p] = (unsigned)e; }
    if (dst_in[e] >= NOUT_BASE)  { unsigned p = atomicAdd(ctri, 1u); listi[p] = (unsigned)e; }
}

// stage [nf[src] | nf[dst] | ef] -> bf16 X rows (21 chunks of 8 cols, pad 144..167 = 0)
__device__ __forceinline__ void stage_edge_x(unsigned short* X, const float* nf, const float* ef,
                                             const int* s_eid, const int* s_src, const int* s_dst, int tid) {
    for (int i = tid; i < 128 * 21; i += THREADS) {
        const int el = i / 21, q = i - el * 21;
        unsigned p0 = 0, p1 = 0, p2 = 0, p3 = 0;
        if (s_eid[el] >= 0 && q < 18) {
            const float* sp;
            if (q < 8)       sp = nf + (size_t)s_src[el] * 64 + q * 8;
            else if (q < 16) sp = nf + (size_t)s_dst[el] * 64 + (q - 8) * 8;
            else             sp = ef + (size_t)s_eid[el] * 16 + (q - 16) * 8;
            const float4 va = *(const float4*)sp, vb = *(const float4*)(sp + 4);
            p0 = f2b(va.x) | ((unsigned)f2b(va.y) << 16);
            p1 = f2b(va.z) | ((unsigned)f2b(va.w) << 16);
            p2 = f2b(vb.x) | ((unsigned)f2b(vb.y) << 16);
            p3 = f2b(vb.z) | ((unsigned)f2b(vb.w) << 16);
        }
        *(uint4*)(X + el * 168 + q * 8) = make_uint4(p0, p1, p2, p3);
    }
}

// ---- o2i edge MLP (MFMA) + scatter-add ----
__global__ __launch_bounds__(THREADS)
void edge_out_mfma(const float* __restrict__ nf, const float* __restrict__ ef,
                   const int* __restrict__ src, const int* __restrict__ dst,
                   const unsigned* __restrict__ list, const unsigned* __restrict__ counter,
                   const unsigned short* __restrict__ wts,
                   const float* __restrict__ b0, const float* __restrict__ b1,
                   const float* __restrict__ b2, const float* __restrict__ b3,
                   const float* __restrict__ b4, float* __restrict__ nfi) {
    __shared__ unsigned short X[128 * 168];
    __shared__ unsigned short Wl[10752];
    __shared__ int s_eid[128], s_src[128], s_dst[128];
    const unsigned total = *counter;
    const unsigned base  = (unsigned)blockIdx.x * 128u;
    if (base >= total) return;
    const int tid = threadIdx.x, lane = tid & 63, wv = tid >> 6;
    if (tid < 128) {
        const unsigned idx = base + (unsigned)tid;
        const int e = (idx < total) ? (int)list[idx] : -1;
        s_eid[tid] = e; s_src[tid] = e >= 0 ? src[e] : 0; s_dst[tid] = e >= 0 ? dst[e] : 0;
    }
    __syncthreads();
    stage_edge_x(X, nf, ef, s_eid, s_src, s_dst, tid);
    stage_w(Wl, wts + OW_O2I0, 10752, tid);
    __syncthreads();
    f32x4 acc[2][4];
    gemm_core<2, 4, 5, 168, 168>(X, Wl, b0, 64, wv, lane, acc);
    writeback<2, 4, 168>(X, acc, wv, lane);
    __syncthreads(); stage_w(Wl, wts + OW_O2I1, 4608, tid); __syncthreads();
    gemm_core<2, 4, 2, 168, 72>(X, Wl, b1, 64, wv, lane, acc);
    writeback<2, 4, 168>(X, acc, wv, lane);
    __syncthreads(); stage_w(Wl, wts + OW_O2I2, 4608, tid); __syncthreads();
    gemm_core<2, 4, 2, 168, 72>(X, Wl, b2, 64, wv, lane, acc);
    writeback<2, 4, 168>(X, acc, wv, lane);
    __syncthreads(); stage_w(Wl, wts + OW_O2I3, 4608, tid); __syncthreads();
    gemm_core<2, 4, 2, 168, 72>(X, Wl, b3, 64, wv, lane, acc);
    writeback<2, 4, 168>(X, acc, wv, lane);
    __syncthreads(); stage_w(Wl, wts + OW_O2I4, 9216, tid); __syncthreads();
    f32x4 acc8[2][8];
    gemm_core<2, 8, 2, 168, 72>(X, Wl, b4, 128, wv, lane, acc8);
    const int r = lane & 15, kg = lane >> 4;
#pragma unroll
    for (int mt = 0; mt < 2; ++mt)
#pragma unroll
        for (int q = 0; q < 4; ++q) {
            const int row = wv * 32 + mt * 16 + kg * 4 + q;
            if (s_eid[row] < 0) continue;
            float* p = nfi + (size_t)s_dst[row] * 128;
#pragma unroll
            for (int nt = 0; nt < 8; ++nt) atomicAdd(p + nt * 16 + r, acc8[mt][nt][q]);
        }
}

// ---- i2o edge MLP (MFMA) + gate + mean/max scatter ----
__global__ __launch_bounds__(THREADS)
void edge_in_mfma(const float* __restrict__ nf, const float* __restrict__ ef,
                  const int* __restrict__ src, const int* __restrict__ dst,
                  const unsigned* __restrict__ list, const unsigned* __restrict__ counter,
                  const unsigned short* __restrict__ wts,
                  const float* __restrict__ b0, const float* __restrict__ b1,
                  const float* __restrict__ b2, const float* __restrict__ b3,
                  float* __restrict__ f1s, unsigned* __restrict__ f2k, unsigned* __restrict__ cnt) {
    __shared__ unsigned short X[128 * 168];
    __shared__ unsigned short Wl[10752];
    __shared__ int s_eid[128], s_src[128], s_dst[128];
    __shared__ float g[128];
    const unsigned total = *counter;
    const unsigned base  = (unsigned)blockIdx.x * 128u;
    if (base >= total) return;
    const int tid = threadIdx.x, lane = tid & 63, wv = tid >> 6;
    if (tid < 128) {
        const unsigned idx = base + (unsigned)tid;
        const int e = (idx < total) ? (int)list[idx] : -1;
        s_eid[tid] = e; s_src[tid] = e >= 0 ? src[e] : 0; s_dst[tid] = e >= 0 ? dst[e] : 0;
    }
    __syncthreads();
    stage_edge_x(X, nf, ef, s_eid, s_src, s_dst, tid);
    stage_w(Wl, wts + OW_I2O0, 10752, tid);
    __syncthreads();
    f32x4 acc[2][4];
    gemm_core<2, 4, 5, 168, 168>(X, Wl, b0, 64, wv, lane, acc);
    writeback<2, 4, 168>(X, acc, wv, lane);
    __syncthreads(); stage_w(Wl, wts + OW_I2O1, 4608, tid); __syncthreads();
    gemm_core<2, 4, 2, 168, 72>(X, Wl, b1, 64, wv, lane, acc);
    writeback<2, 4, 168>(X, acc, wv, lane);
    __syncthreads(); stage_w(Wl, wts + OW_I2O2, 4608, tid); __syncthreads();
    gemm_core<2, 4, 2, 168, 72>(X, Wl, b2, 64, wv, lane, acc);
    writeback<2, 4, 168>(X, acc, wv, lane);
    __syncthreads(); stage_w(Wl, wts + OW_I2O3, 5760, tid); __syncthreads();
    f32x4 acc5[2][5];
    gemm_core<2, 5, 2, 168, 72>(X, Wl, b3, 65, wv, lane, acc5);
    const int r = lane & 15, kg = lane >> 4;
    if (r == 0) {
#pragma unroll
        for (int mt = 0; mt < 2; ++mt)
#pragma unroll
            for (int q = 0; q < 4; ++q) g[wv * 32 + mt * 16 + kg * 4 + q] = acc5[mt][4][q];
    }
    __syncthreads();
#pragma unroll
    for (int mt = 0; mt < 2; ++mt)
#pragma unroll
        for (int q = 0; q < 4; ++q) {
            const int row = wv * 32 + mt * 16 + kg * 4 + q;
            if (s_eid[row] < 0) continue;
            const float kgv = 1.0f / (1.0f + expf(-g[row]));
            const int rr = s_dst[row] - NOUT_BASE;
#pragma unroll
            for (int nt = 0; nt < 5; ++nt) {
                const int c = nt * 16 + r;
                if (c == 0 || c > 64) continue;
                const float v = acc5[mt][nt][q] * kgv;
                if (c <= 32) atomicAdd(f1s + (size_t)rr * 32 + (c - 1), v);
                else         atomicMax(f2k + (size_t)rr * 32 + (c - 33), fkey(v));
            }
            if (r == 0) atomicAdd(cnt + rr, 1u);
        }
}

// ---- ri node MLP (192->64->64->64->64), nodes [0, NIN) ----
__global__ __launch_bounds__(THREADS)
void node_ri_mfma(const float* __restrict__ nf, const float* __restrict__ nfi,
                  const unsigned short* __restrict__ wts,
                  const float* __restrict__ b0, const float* __restrict__ b1,
                  const float* __restrict__ b2, const float* __restrict__ b3,
                  float* __restrict__ out) {
    __shared__ unsigned short X[64 * 200];
    __shared__ unsigned short Wl[12800];
    const int tid = threadIdx.x, lane = tid & 63, wv = tid >> 6;
    const int base = blockIdx.x * 64;
    for (int i = tid; i < 64 * 25; i += THREADS) {
        const int el = i / 25, q = i - el * 25;
        unsigned p0 = 0, p1 = 0, p2 = 0, p3 = 0;
        if (q < 24) {
            const float* sp = (q < 8) ? nf + (size_t)(base + el) * 64 + q * 8
                                      : nfi + (size_t)(base + el) * 128 + (q - 8) * 8;
            const float4 va = *(const float4*)sp, vb = *(const float4*)(sp + 4);
            p0 = f2b(va.x) | ((unsigned)f2b(va.y) << 16);
            p1 = f2b(va.z) | ((unsigned)f2b(va.w) << 16);
            p2 = f2b(vb.x) | ((unsigned)f2b(vb.y) << 16);
            p3 = f2b(vb.z) | ((unsigned)f2b(vb.w) << 16);
        }
        *(uint4*)(X + el * 200 + q * 8) = make_uint4(p0, p1, p2, p3);
    }
    stage_w(Wl, wts + OW_RI0, 12800, tid);
    __syncthreads();
    f32x4 acc[1][4];
    gemm_core<1, 4, 6, 200, 200>(X, Wl, b0, 64, wv, lane, acc);
    writeback<1, 4, 200>(X, acc, wv, lane);
    __syncthreads(); stage_w(Wl, wts + OW_RI1, 4608, tid); __syncthreads();
    gemm_core<1, 4, 2, 200, 72>(X, Wl, b1, 64, wv, lane, acc);
    writeback<1, 4, 200>(X, acc, wv, lane);
    __syncthreads(); stage_w(Wl, wts + OW_RI2, 4608, tid); __syncthreads();
    gemm_core<1, 4, 2, 200, 72>(X, Wl, b2, 64, wv, lane, acc);
    writeback<1, 4, 200>(X, acc, wv, lane);
    __syncthreads(); stage_w(Wl, wts + OW_RI3, 4608, tid); __syncthreads();
    gemm_core<1, 4, 2, 200, 72>(X, Wl, b3, 64, wv, lane, acc);
    const int r = lane & 15, kg = lane >> 4;
#pragma unroll
    for (int nt = 0; nt < 4; ++nt)
#pragma unroll
        for (int q = 0; q < 4; ++q)
            out[(size_t)(base + wv * 16 + kg * 4 + q) * 64 + nt * 16 + r] = acc[0][nt][q];
}

// ---- ro node MLP (128->64->64->64->64), nodes [NOUT_BASE, N) ----
__global__ __launch_bounds__(THREADS)
void node_ro_mfma(const float* __restrict__ nf, const float* __restrict__ f1s,
                  const unsigned* __restrict__ f2k, const unsigned* __restrict__ cnt,
                  const unsigned short* __restrict__ wts,
                  const float* __restrict__ b0, const float* __restrict__ b1,
                  const float* __restrict__ b2, const float* __restrict__ b3,
                  float* __restrict__ out) {
    __shared__ unsigned short X[64 * 136];
    __shared__ unsigned short Wl[8704];
    const int tid = threadIdx.x, lane = tid & 63, wv = tid >> 6;
    const int rbase = blockIdx.x * 64;           // node = NOUT_BASE + rbase + el
    for (int i = tid; i < 64 * 17; i += THREADS) {
        const int el = i / 17, q = i - el * 17;
        const int rr = rbase + el;
        unsigned p0 = 0, p1 = 0, p2 = 0, p3 = 0;
        if (q < 16) {
            float v[8];
            if (q < 8) {
                const float* sp = nf + (size_t)(NOUT_BASE + rr) * 64 + q * 8;
                const float4 va = *(const float4*)sp, vb = *(const float4*)(sp + 4);
                v[0]=va.x; v[1]=va.y; v[2]=va.z; v[3]=va.w; v[4]=vb.x; v[5]=vb.y; v[6]=vb.z; v[7]=vb.w;
            } else {
                const unsigned cc = cnt[rr];
                if (q < 12) {
                    const float inv = 1.0f / fmaxf((float)cc, 1.0f);
#pragma unroll
                    for (int j = 0; j < 8; ++j) v[j] = f1s[(size_t)rr * 32 + (q - 8) * 8 + j] * inv;
                } else {
#pragma unroll
                    for (int j = 0; j < 8; ++j)
                        v[j] = (cc > 0u) ? funkey(f2k[(size_t)rr * 32 + (q - 12) * 8 + j]) : 0.0f;
                }
            }
            p0 = f2b(v[0]) | ((unsigned)f2b(v[1]) << 16);
            p1 = f2b(v[2]) | ((unsigned)f2b(v[3]) << 16);
            p2 = f2b(v[4]) | ((unsigned)f2b(v[5]) << 16);
            p3 = f2b(v[6]) | ((unsigned)f2b(v[7]) << 16);
        }
        *(uint4*)(X + el * 136 + q * 8) = make_uint4(p0, p1, p2, p3);
    }
    stage_w(Wl, wts + OW_RO0, 8704, tid);
    __syncthreads();
    f32x4 acc[1][4];
    gemm_core<1, 4, 4, 136, 136>(X, Wl, b0, 64, wv, lane, acc);
    writeback<1, 4, 136>(X, acc, wv, lane);
    __syncthreads(); stage_w(Wl, wts + OW_RO1, 4608, tid); __syncthreads();
    gemm_core<1, 4, 2, 136, 72>(X, Wl, b1, 64, wv, lane, acc);
    writeback<1, 4, 136>(X, acc, wv, lane);
    __syncthreads(); stage_w(Wl, wts + OW_RO2, 4608, tid); __syncthreads();
    gemm_core<1, 4, 2, 136, 72>(X, Wl, b2, 64, wv, lane, acc);
    writeback<1, 4, 136>(X, acc, wv, lane);
    __syncthreads(); stage_w(Wl, wts + OW_RO3, 4608, tid); __syncthreads();
    gemm_core<1, 4, 2, 136, 72>(X, Wl, b3, 64, wv, lane, acc);
    const int r = lane & 15, kg = lane >> 4;
#pragma unroll
    for (int nt = 0; nt < 4; ++nt)
#pragma unroll
        for (int q = 0; q < 4; ++q)
            out[(size_t)(NOUT_BASE + rbase + wv * 16 + kg * 4 + q) * 64 + nt * 16 + r] = acc[0][nt][q];
}

extern "C" void kernel_launch(void* const* d_in, const int* in_sizes, int n_in,
                              void* d_out, int out_size, void* d_ws, size_t ws_size,
                              hipStream_t stream) {
    const float* nf     = (const float*)d_in[0];
    const float* ef_out = (const float*)d_in[1];
    const float* ef_in  = (const float*)d_in[2];
    const float* o2i_w[5] = {(const float*)d_in[3], (const float*)d_in[5], (const float*)d_in[7], (const float*)d_in[9], (const float*)d_in[11]};
    const float* o2i_b[5] = {(const float*)d_in[4], (const float*)d_in[6], (const float*)d_in[8], (const float*)d_in[10], (const float*)d_in[12]};
    const float* i2o_w[4] = {(const float*)d_in[13], (const float*)d_in[15], (const float*)d_in[17], (const float*)d_in[19]};
    const float* i2o_b[4] = {(const float*)d_in[14], (const float*)d_in[16], (const float*)d_in[18], (const float*)d_in[20]};
    const float* ri_w[4]  = {(const float*)d_in[21], (const float*)d_in[23], (const float*)d_in[25], (const float*)d_in[27]};
    const float* ri_b[4]  = {(const float*)d_in[22], (const float*)d_in[24], (const float*)d_in[26], (const float*)d_in[28]};
    const float* ro_w[4]  = {(const float*)d_in[29], (const float*)d_in[31], (const float*)d_in[33], (const float*)d_in[35]};
    const float* ro_b[4]  = {(const float*)d_in[30], (const float*)d_in[32], (const float*)d_in[34], (const float*)d_in[36]};
    const int* src_out  = (const int*)d_in[37];
    const int* dst_out  = (const int*)d_in[38];
    const int* src_in   = (const int*)d_in[39];
    const int* dst_in   = (const int*)d_in[40];

    unsigned* ws   = (unsigned*)d_ws;
    float*    nfi  = (float*)(ws + OFF_NFI);
    float*    f1s  = (float*)(ws + OFF_F1);
    unsigned* f2k  = ws + OFF_F2;
    unsigned* cnt  = ws + OFF_CNT;
    unsigned* ctro = ws + OFF_CTRO;
    unsigned* ctri = ws + OFF_CTRI;
    unsigned* lsto = ws + OFF_LISTO;
    unsigned* lsti = ws + OFF_LISTI;
    unsigned short* wts = (unsigned short*)(ws + OFF_WB);

    hipMemsetAsync(d_ws, 0, OFF_LISTO * sizeof(unsigned), stream);
    hipMemsetAsync((char*)d_out + (size_t)NIN * 64 * sizeof(float), 0,
                   (size_t)(NOUT_BASE - NIN) * 64 * sizeof(float), stream);

    WTab t;
    t.d[0]  = {o2i_w[0], 144,  64, 168,  64, OW_O2I0};
    t.d[1]  = {o2i_w[1],  64,  64,  72,  64, OW_O2I1};
    t.d[2]  = {o2i_w[2],  64,  64,  72,  64, OW_O2I2};
    t.d[3]  = {o2i_w[3],  64,  64,  72,  64, OW_O2I3};
    t.d[4]  = {o2i_w[4],  64, 128,  72, 128, OW_O2I4};
    t.d[5]  = {i2o_w[0], 144,  64, 168,  64, OW_I2O0};
    t.d[6]  = {i2o_w[1],  64,  64,  72,  64, OW_I2O1};
    t.d[7]  = {i2o_w[2],  64,  64,  72,  64, OW_I2O2};
    t.d[8]  = {i2o_w[3],  64,  65,  72,  80, OW_I2O3};
    t.d[9]  = {ri_w[0],  192,  64, 200,  64, OW_RI0};
    t.d[10] = {ri_w[1],   64,  64,  72,  64, OW_RI1};
    t.d[11] = {ri_w[2],   64,  64,  72,  64, OW_RI2};
    t.d[12] = {ri_w[3],   64,  64,  72,  64, OW_RI3};
    t.d[13] = {ro_w[0],  128,  64, 136,  64, OW_RO0};
    t.d[14] = {ro_w[1],   64,  64,  72,  64, OW_RO1};
    t.d[15] = {ro_w[2],   64,  64,  72,  64, OW_RO2};
    t.d[16] = {ro_w[3],   64,  64,  72,  64, OW_RO3};
    convert_w<<<dim3(50, 17), THREADS, 0, stream>>>(t, wts);

    compact_k<<<(N_EDGES + THREADS - 1) / THREADS, THREADS, 0, stream>>>(
        dst_out, dst_in, ctro, ctri, lsto, lsti);

    edge_out_mfma<<<(N_EDGES + 127) / 128, THREADS, 0, stream>>>(
        nf, ef_out, src_out, dst_out, lsto, ctro, wts,
        o2i_b[0], o2i_b[1], o2i_b[2], o2i_b[3], o2i_b[4], nfi);

    edge_in_mfma<<<(N_EDGES + 127) / 128, THREADS, 0, stream>>>(
        nf, ef_in, src_in, dst_in, lsti, ctri, wts,
        i2o_b[0], i2o_b[1], i2o_b[2], i2o_b[3], f1s, f2k, cnt);

    node_ri_mfma<<<NIN / 64, THREADS, 0, stream>>>(
        nf, nfi, wts, ri_b[0], ri_b[1], ri_b[2], ri_b[3], (float*)d_out);

    node_ro_mfma<<<NOUT / 64, THREADS, 0, stream>>>(
        nf, f1s, f2k, cnt, wts, ro_b[0], ro_b[1], ro_b[2], ro_b[3], (float*)d_out);
}

// Round 4
// 715.305 us; speedup vs baseline: 5.1362x; 1.0010x over previous
//
#include <hip/hip_runtime.h>
#include <cmath>

#define THREADS 256

static constexpr int N_NODES   = 100000;
static constexpr int N_EDGES   = 800000;
static constexpr int NIN       = 40000;   // input_mask: n < NIN
static constexpr int NOUT_BASE = 60000;   // output_mask: n >= NOUT_BASE
static constexpr int NOUT      = 40000;

// ---- workspace layout (32-bit words) ----
static constexpr size_t OFF_NFI   = 0;                                // 40000*128 f32
static constexpr size_t OFF_F1    = OFF_NFI  + (size_t)NIN  * 128;    // 40000*32  f32
static constexpr size_t OFF_F2    = OFF_F1   + (size_t)NOUT * 32;     // 40000*32  u32 (keys)
static constexpr size_t OFF_CNT   = OFF_F2   + (size_t)NOUT * 32;     // 40000 u32
static constexpr size_t OFF_CTRO  = OFF_CNT  + NOUT;                  // 1 u32
static constexpr size_t OFF_CTRI  = OFF_CTRO + 1;                     // 1 u32
static constexpr size_t OFF_LISTO = OFF_CTRI + 1;                     // E u32
static constexpr size_t OFF_LISTI = OFF_LISTO + N_EDGES;              // E u32
static constexpr size_t OFF_WB    = OFF_LISTI + N_EDGES;              // bf16 weights region

// converted-weight offsets (ushort units). [n][k] layout, strides = Kp+8 (bank pad)
static constexpr unsigned OW_O2I0 = 0;       // 64 x 168
static constexpr unsigned OW_O2I1 = 10752;   // 64 x 72
static constexpr unsigned OW_O2I2 = 15360;
static constexpr unsigned OW_O2I3 = 19968;
static constexpr unsigned OW_O2I4 = 24576;   // 128 x 72
static constexpr unsigned OW_I2O0 = 33792;   // 64 x 168
static constexpr unsigned OW_I2O1 = 44544;
static constexpr unsigned OW_I2O2 = 49152;
static constexpr unsigned OW_I2O3 = 53760;   // 80 x 72 (N=65 padded)
static constexpr unsigned OW_RI0  = 59520;   // 64 x 200
static constexpr unsigned OW_RI1  = 72320;
static constexpr unsigned OW_RI2  = 76928;
static constexpr unsigned OW_RI3  = 81536;
static constexpr unsigned OW_RO0  = 86144;   // 64 x 136
static constexpr unsigned OW_RO1  = 94848;
static constexpr unsigned OW_RO2  = 99456;
static constexpr unsigned OW_RO3  = 104064;  // end 108672

typedef __attribute__((ext_vector_type(8))) short short8;
typedef __attribute__((ext_vector_type(4))) float f32x4;

__device__ __forceinline__ float lrelu(float x) { return x > 0.0f ? x : 0.2f * x; }

__device__ __forceinline__ unsigned short f2b(float f) {   // RNE f32->bf16
    unsigned u = __float_as_uint(f);
    return (unsigned short)((u + 0x7fffu + ((u >> 16) & 1u)) >> 16);
}
__device__ __forceinline__ unsigned fkey(float f) {
    unsigned u = __float_as_uint(f);
    return (u & 0x80000000u) ? ~u : (u | 0x80000000u);
}
__device__ __forceinline__ float funkey(unsigned k) {
    return (k & 0x80000000u) ? __uint_as_float(k & 0x7fffffffu) : __uint_as_float(~k);
}

// copy n ushorts (n % 8 == 0, 16B aligned) global -> LDS
__device__ __forceinline__ void stage_w(unsigned short* dst, const unsigned short* src, int n, int tid) {
    for (int i = tid * 8; i < n; i += THREADS * 8)
        *(uint4*)(dst + i) = *(const uint4*)(src + i);
}

// One dense layer tile: MT m-tiles (16 rows each) per wave, NT n-tiles, KT k-steps of 32.
// X: bf16 LDS activations [rows][XSTR]; W: bf16 LDS weights [n][WSTR] (pre-transposed).
// A-frag: m=lane&15, k=(lane>>4)*8+j ; B-frag: n=lane&15, same k ; D: col=lane&15, row=(lane>>4)*4+reg.
template<int MT, int NT, int KT, int XSTR, int WSTR>
__device__ __forceinline__ void gemm_core(const unsigned short* X, const unsigned short* W,
                                          const float* bias, int biasN, int wv, int lane,
                                          f32x4 (&acc)[MT][NT]) {
    const int r = lane & 15, kg = lane >> 4;
    short8 a[MT][KT];
#pragma unroll
    for (int mt = 0; mt < MT; ++mt)
#pragma unroll
        for (int kk = 0; kk < KT; ++kk)
            a[mt][kk] = *(const short8*)(X + (wv * 16 * MT + mt * 16 + r) * XSTR + kk * 32 + kg * 8);
#pragma unroll
    for (int nt = 0; nt < NT; ++nt) {
        const int c = nt * 16 + r;
        const float bv = (c < biasN) ? bias[c] : 0.0f;
#pragma unroll
        for (int mt = 0; mt < MT; ++mt) acc[mt][nt] = (f32x4){bv, bv, bv, bv};
    }
#pragma unroll
    for (int kk = 0; kk < KT; ++kk)
#pragma unroll
        for (int nt = 0; nt < NT; ++nt) {
            short8 b = *(const short8*)(W + (nt * 16 + r) * WSTR + kk * 32 + kg * 8);
#pragma unroll
            for (int mt = 0; mt < MT; ++mt)
                acc[mt][nt] = __builtin_amdgcn_mfma_f32_16x16x32_bf16(a[mt][kk], b, acc[mt][nt], 0, 0, 0);
        }
}

// leaky-relu + bf16 + in-place writeback to X (each wave touches only its own rows)
template<int MT, int NT, int XSTR>
__device__ __forceinline__ void writeback(unsigned short* X, f32x4 (&acc)[MT][NT], int wv, int lane) {
    const int r = lane & 15, kg = lane >> 4;
#pragma unroll
    for (int mt = 0; mt < MT; ++mt)
#pragma unroll
        for (int nt = 0; nt < NT; ++nt)
#pragma unroll
            for (int q = 0; q < 4; ++q)
                X[(wv * 16 * MT + mt * 16 + kg * 4 + q) * XSTR + nt * 16 + r] = f2b(lrelu(acc[mt][nt][q]));
}

// ---- weight conversion: f32 [K][N] -> bf16 [Np][stride] transposed, zero-padded ----
struct WDesc { const float* w; int K, N, stride, Np; unsigned off; };
struct WTab { WDesc d[17]; };

__global__ __launch_bounds__(THREADS)
void convert_w(WTab t, unsigned short* wts) {
    const WDesc d = t.d[blockIdx.y];
    const int idx = blockIdx.x * THREADS + threadIdx.x;
    const int tot = d.Np * d.stride;
    if (idx >= tot) return;
    const int n = idx / d.stride, k = idx - n * d.stride;
    const float v = (k < d.K && n < d.N) ? d.w[(size_t)k * d.N + n] : 0.0f;
    wts[d.off + idx] = f2b(v);
}

// ---- edge compaction: wave-aggregated atomics (1 atomicAdd per wave per list) ----
__global__ __launch_bounds__(THREADS)
void compact_k(const int* __restrict__ dst_out, const int* __restrict__ dst_in,
               unsigned* __restrict__ ctro, unsigned* __restrict__ ctri,
               unsigned* __restrict__ listo, unsigned* __restrict__ listi) {
    const int e = blockIdx.x * THREADS + threadIdx.x;   // grid covers exactly N_EDGES
    const int lane = threadIdx.x & 63;
    const unsigned long long lm = (1ull << lane) - 1ull;

    const bool po = dst_out[e] < NIN;
    unsigned long long mo = __ballot(po);
    unsigned bo = 0;
    if (lane == 0) bo = mo ? atomicAdd(ctro, (unsigned)__popcll(mo)) : 0u;
    bo = (unsigned)__shfl((int)bo, 0);
    if (po) listo[bo + __popcll(mo & lm)] = (unsigned)e;

    const bool pi = dst_in[e] >= NOUT_BASE;
    unsigned long long mi = __ballot(pi);
    unsigned bi = 0;
    if (lane == 0) bi = mi ? atomicAdd(ctri, (unsigned)__popcll(mi)) : 0u;
    bi = (unsigned)__shfl((int)bi, 0);
    if (pi) listi[bi + __popcll(mi & lm)] = (unsigned)e;
}

// stage [nf[src] | nf[dst] | ef] -> bf16 X rows (21 chunks of 8 cols, pad 144..167 = 0)
__device__ __forceinline__ void stage_edge_x(unsigned short* X, const float* nf, const float* ef,
                                             const int* s_eid, const int* s_src, const int* s_dst, int tid) {
    for (int i = tid; i < 128 * 21; i += THREADS) {
        const int el = i / 21, q = i - el * 21;
        unsigned p0 = 0, p1 = 0, p2 = 0, p3 = 0;
        if (s_eid[el] >= 0 && q < 18) {
            const float* sp;
            if (q < 8)       sp = nf + (size_t)s_src[el] * 64 + q * 8;
            else if (q < 16) sp = nf + (size_t)s_dst[el] * 64 + (q - 8) * 8;
            else             sp = ef + (size_t)s_eid[el] * 16 + (q - 16) * 8;
            const float4 va = *(const float4*)sp, vb = *(const float4*)(sp + 4);
            p0 = f2b(va.x) | ((unsigned)f2b(va.y) << 16);
            p1 = f2b(va.z) | ((unsigned)f2b(va.w) << 16);
            p2 = f2b(vb.x) | ((unsigned)f2b(vb.y) << 16);
            p3 = f2b(vb.z) | ((unsigned)f2b(vb.w) << 16);
        }
        *(uint4*)(X + el * 168 + q * 8) = make_uint4(p0, p1, p2, p3);
    }
}

// ---- o2i edge MLP (MFMA) + scatter-add ----
__global__ __launch_bounds__(THREADS)
void edge_out_mfma(const float* __restrict__ nf, const float* __restrict__ ef,
                   const int* __restrict__ src, const int* __restrict__ dst,
                   const unsigned* __restrict__ list, const unsigned* __restrict__ counter,
                   const unsigned short* __restrict__ wts,
                   const float* __restrict__ b0, const float* __restrict__ b1,
                   const float* __restrict__ b2, const float* __restrict__ b3,
                   const float* __restrict__ b4, float* __restrict__ nfi) {
    __shared__ unsigned short X[128 * 168];
    __shared__ unsigned short Wl[10752];
    __shared__ int s_eid[128], s_src[128], s_dst[128];
    const unsigned total = *counter;
    const unsigned base  = (unsigned)blockIdx.x * 128u;
    if (base >= total) return;
    const int tid = threadIdx.x, lane = tid & 63, wv = tid >> 6;
    if (tid < 128) {
        const unsigned idx = base + (unsigned)tid;
        const int e = (idx < total) ? (int)list[idx] : -1;
        s_eid[tid] = e; s_src[tid] = e >= 0 ? src[e] : 0; s_dst[tid] = e >= 0 ? dst[e] : 0;
    }
    __syncthreads();
    stage_edge_x(X, nf, ef, s_eid, s_src, s_dst, tid);
    stage_w(Wl, wts + OW_O2I0, 10752, tid);
    __syncthreads();
    f32x4 acc[2][4];
    gemm_core<2, 4, 5, 168, 168>(X, Wl, b0, 64, wv, lane, acc);
    writeback<2, 4, 168>(X, acc, wv, lane);
    __syncthreads(); stage_w(Wl, wts + OW_O2I1, 4608, tid); __syncthreads();
    gemm_core<2, 4, 2, 168, 72>(X, Wl, b1, 64, wv, lane, acc);
    writeback<2, 4, 168>(X, acc, wv, lane);
    __syncthreads(); stage_w(Wl, wts + OW_O2I2, 4608, tid); __syncthreads();
    gemm_core<2, 4, 2, 168, 72>(X, Wl, b2, 64, wv, lane, acc);
    writeback<2, 4, 168>(X, acc, wv, lane);
    __syncthreads(); stage_w(Wl, wts + OW_O2I3, 4608, tid); __syncthreads();
    gemm_core<2, 4, 2, 168, 72>(X, Wl, b3, 64, wv, lane, acc);
    writeback<2, 4, 168>(X, acc, wv, lane);
    __syncthreads(); stage_w(Wl, wts + OW_O2I4, 9216, tid); __syncthreads();
    f32x4 acc8[2][8];
    gemm_core<2, 8, 2, 168, 72>(X, Wl, b4, 128, wv, lane, acc8);
    const int r = lane & 15, kg = lane >> 4;
#pragma unroll
    for (int mt = 0; mt < 2; ++mt)
#pragma unroll
        for (int q = 0; q < 4; ++q) {
            const int row = wv * 32 + mt * 16 + kg * 4 + q;
            if (s_eid[row] < 0) continue;
            float* p = nfi + (size_t)s_dst[row] * 128;
#pragma unroll
            for (int nt = 0; nt < 8; ++nt) atomicAdd(p + nt * 16 + r, acc8[mt][nt][q]);
        }
}

// ---- i2o edge MLP (MFMA) + gate + mean/max scatter ----
__global__ __launch_bounds__(THREADS)
void edge_in_mfma(const float* __restrict__ nf, const float* __restrict__ ef,
                  const int* __restrict__ src, const int* __restrict__ dst,
                  const unsigned* __restrict__ list, const unsigned* __restrict__ counter,
                  const unsigned short* __restrict__ wts,
                  const float* __restrict__ b0, const float* __restrict__ b1,
                  const float* __restrict__ b2, const float* __restrict__ b3,
                  float* __restrict__ f1s, unsigned* __restrict__ f2k, unsigned* __restrict__ cnt) {
    __shared__ unsigned short X[128 * 168];
    __shared__ unsigned short Wl[10752];
    __shared__ int s_eid[128], s_src[128], s_dst[128];
    __shared__ float g[128];
    const unsigned total = *counter;
    const unsigned base  = (unsigned)blockIdx.x * 128u;
    if (base >= total) return;
    const int tid = threadIdx.x, lane = tid & 63, wv = tid >> 6;
    if (tid < 128) {
        const unsigned idx = base + (unsigned)tid;
        const int e = (idx < total) ? (int)list[idx] : -1;
        s_eid[tid] = e; s_src[tid] = e >= 0 ? src[e] : 0; s_dst[tid] = e >= 0 ? dst[e] : 0;
    }
    __syncthreads();
    stage_edge_x(X, nf, ef, s_eid, s_src, s_dst, tid);
    stage_w(Wl, wts + OW_I2O0, 10752, tid);
    __syncthreads();
    f32x4 acc[2][4];
    gemm_core<2, 4, 5, 168, 168>(X, Wl, b0, 64, wv, lane, acc);
    writeback<2, 4, 168>(X, acc, wv, lane);
    __syncthreads(); stage_w(Wl, wts + OW_I2O1, 4608, tid); __syncthreads();
    gemm_core<2, 4, 2, 168, 72>(X, Wl, b1, 64, wv, lane, acc);
    writeback<2, 4, 168>(X, acc, wv, lane);
    __syncthreads(); stage_w(Wl, wts + OW_I2O2, 4608, tid); __syncthreads();
    gemm_core<2, 4, 2, 168, 72>(X, Wl, b2, 64, wv, lane, acc);
    writeback<2, 4, 168>(X, acc, wv, lane);
    __syncthreads(); stage_w(Wl, wts + OW_I2O3, 5760, tid); __syncthreads();
    f32x4 acc5[2][5];
    gemm_core<2, 5, 2, 168, 72>(X, Wl, b3, 65, wv, lane, acc5);
    const int r = lane & 15, kg = lane >> 4;
    if (r == 0) {
#pragma unroll
        for (int mt = 0; mt < 2; ++mt)
#pragma unroll
            for (int q = 0; q < 4; ++q) g[wv * 32 + mt * 16 + kg * 4 + q] = acc5[mt][4][q];
    }
    __syncthreads();
#pragma unroll
    for (int mt = 0; mt < 2; ++mt)
#pragma unroll
        for (int q = 0; q < 4; ++q) {
            const int row = wv * 32 + mt * 16 + kg * 4 + q;
            if (s_eid[row] < 0) continue;
            const float kgv = 1.0f / (1.0f + expf(-g[row]));
            const int rr = s_dst[row] - NOUT_BASE;
#pragma unroll
            for (int nt = 0; nt < 5; ++nt) {
                const int c = nt * 16 + r;
                if (c == 0 || c > 64) continue;
                const float v = acc5[mt][nt][q] * kgv;
                if (c <= 32) atomicAdd(f1s + (size_t)rr * 32 + (c - 1), v);
                else         atomicMax(f2k + (size_t)rr * 32 + (c - 33), fkey(v));
            }
            if (r == 0) atomicAdd(cnt + rr, 1u);
        }
}

// ---- ri node MLP (192->64->64->64->64), nodes [0, NIN) ----
__global__ __launch_bounds__(THREADS)
void node_ri_mfma(const float* __restrict__ nf, const float* __restrict__ nfi,
                  const unsigned short* __restrict__ wts,
                  const float* __restrict__ b0, const float* __restrict__ b1,
                  const float* __restrict__ b2, const float* __restrict__ b3,
                  float* __restrict__ out) {
    __shared__ unsigned short X[64 * 200];
    __shared__ unsigned short Wl[12800];
    const int tid = threadIdx.x, lane = tid & 63, wv = tid >> 6;
    const int base = blockIdx.x * 64;
    for (int i = tid; i < 64 * 25; i += THREADS) {
        const int el = i / 25, q = i - el * 25;
        unsigned p0 = 0, p1 = 0, p2 = 0, p3 = 0;
        if (q < 24) {
            const float* sp = (q < 8) ? nf + (size_t)(base + el) * 64 + q * 8
                                      : nfi + (size_t)(base + el) * 128 + (q - 8) * 8;
            const float4 va = *(const float4*)sp, vb = *(const float4*)(sp + 4);
            p0 = f2b(va.x) | ((unsigned)f2b(va.y) << 16);
            p1 = f2b(va.z) | ((unsigned)f2b(va.w) << 16);
            p2 = f2b(vb.x) | ((unsigned)f2b(vb.y) << 16);
            p3 = f2b(vb.z) | ((unsigned)f2b(vb.w) << 16);
        }
        *(uint4*)(X + el * 200 + q * 8) = make_uint4(p0, p1, p2, p3);
    }
    stage_w(Wl, wts + OW_RI0, 12800, tid);
    __syncthreads();
    f32x4 acc[1][4];
    gemm_core<1, 4, 6, 200, 200>(X, Wl, b0, 64, wv, lane, acc);
    writeback<1, 4, 200>(X, acc, wv, lane);
    __syncthreads(); stage_w(Wl, wts + OW_RI1, 4608, tid); __syncthreads();
    gemm_core<1, 4, 2, 200, 72>(X, Wl, b1, 64, wv, lane, acc);
    writeback<1, 4, 200>(X, acc, wv, lane);
    __syncthreads(); stage_w(Wl, wts + OW_RI2, 4608, tid); __syncthreads();
    gemm_core<1, 4, 2, 200, 72>(X, Wl, b2, 64, wv, lane, acc);
    writeback<1, 4, 200>(X, acc, wv, lane);
    __syncthreads(); stage_w(Wl, wts + OW_RI3, 4608, tid); __syncthreads();
    gemm_core<1, 4, 2, 200, 72>(X, Wl, b3, 64, wv, lane, acc);
    const int r = lane & 15, kg = lane >> 4;
#pragma unroll
    for (int nt = 0; nt < 4; ++nt)
#pragma unroll
        for (int q = 0; q < 4; ++q)
            out[(size_t)(base + wv * 16 + kg * 4 + q) * 64 + nt * 16 + r] = acc[0][nt][q];
}

// ---- ro node MLP (128->64->64->64->64), nodes [NOUT_BASE, N) ----
__global__ __launch_bounds__(THREADS)
void node_ro_mfma(const float* __restrict__ nf, const float* __restrict__ f1s,
                  const unsigned* __restrict__ f2k, const unsigned* __restrict__ cnt,
                  const unsigned short* __restrict__ wts,
                  const float* __restrict__ b0, const float* __restrict__ b1,
                  const float* __restrict__ b2, const float* __restrict__ b3,
                  float* __restrict__ out) {
    __shared__ unsigned short X[64 * 136];
    __shared__ unsigned short Wl[8704];
    const int tid = threadIdx.x, lane = tid & 63, wv = tid >> 6;
    const int rbase = blockIdx.x * 64;           // node = NOUT_BASE + rbase + el
    for (int i = tid; i < 64 * 17; i += THREADS) {
        const int el = i / 17, q = i - el * 17;
        const int rr = rbase + el;
        unsigned p0 = 0, p1 = 0, p2 = 0, p3 = 0;
        if (q < 16) {
            float v[8];
            if (q < 8) {
                const float* sp = nf + (size_t)(NOUT_BASE + rr) * 64 + q * 8;
                const float4 va = *(const float4*)sp, vb = *(const float4*)(sp + 4);
                v[0]=va.x; v[1]=va.y; v[2]=va.z; v[3]=va.w; v[4]=vb.x; v[5]=vb.y; v[6]=vb.z; v[7]=vb.w;
            } else {
                const unsigned cc = cnt[rr];
                if (q < 12) {
                    const float inv = 1.0f / fmaxf((float)cc, 1.0f);
#pragma unroll
                    for (int j = 0; j < 8; ++j) v[j] = f1s[(size_t)rr * 32 + (q - 8) * 8 + j] * inv;
                } else {
#pragma unroll
                    for (int j = 0; j < 8; ++j)
                        v[j] = (cc > 0u) ? funkey(f2k[(size_t)rr * 32 + (q - 12) * 8 + j]) : 0.0f;
                }
            }
            p0 = f2b(v[0]) | ((unsigned)f2b(v[1]) << 16);
            p1 = f2b(v[2]) | ((unsigned)f2b(v[3]) << 16);
            p2 = f2b(v[4]) | ((unsigned)f2b(v[5]) << 16);
            p3 = f2b(v[6]) | ((unsigned)f2b(v[7]) << 16);
        }
        *(uint4*)(X + el * 136 + q * 8) = make_uint4(p0, p1, p2, p3);
    }
    stage_w(Wl, wts + OW_RO0, 8704, tid);
    __syncthreads();
    f32x4 acc[1][4];
    gemm_core<1, 4, 4, 136, 136>(X, Wl, b0, 64, wv, lane, acc);
    writeback<1, 4, 136>(X, acc, wv, lane);
    __syncthreads(); stage_w(Wl, wts + OW_RO1, 4608, tid); __syncthreads();
    gemm_core<1, 4, 2, 136, 72>(X, Wl, b1, 64, wv, lane, acc);
    writeback<1, 4, 136>(X, acc, wv, lane);
    __syncthreads(); stage_w(Wl, wts + OW_RO2, 4608, tid); __syncthreads();
    gemm_core<1, 4, 2, 136, 72>(X, Wl, b2, 64, wv, lane, acc);
    writeback<1, 4, 136>(X, acc, wv, lane);
    __syncthreads(); stage_w(Wl, wts + OW_RO3, 4608, tid); __syncthreads();
    gemm_core<1, 4, 2, 136, 72>(X, Wl, b3, 64, wv, lane, acc);
    const int r = lane & 15, kg = lane >> 4;
#pragma unroll
    for (int nt = 0; nt < 4; ++nt)
#pragma unroll
        for (int q = 0; q < 4; ++q)
            out[(size_t)(NOUT_BASE + rbase + wv * 16 + kg * 4 + q) * 64 + nt * 16 + r] = acc[0][nt][q];
}

extern "C" void kernel_launch(void* const* d_in, const int* in_sizes, int n_in,
                              void* d_out, int out_size, void* d_ws, size_t ws_size,
                              hipStream_t stream) {
    const float* nf     = (const float*)d_in[0];
    const float* ef_out = (const float*)d_in[1];
    const float* ef_in  = (const float*)d_in[2];
    const float* o2i_w[5] = {(const float*)d_in[3], (const float*)d_in[5], (const float*)d_in[7], (const float*)d_in[9], (const float*)d_in[11]};
    const float* o2i_b[5] = {(const float*)d_in[4], (const float*)d_in[6], (const float*)d_in[8], (const float*)d_in[10], (const float*)d_in[12]};
    const float* i2o_w[4] = {(const float*)d_in[13], (const float*)d_in[15], (const float*)d_in[17], (const float*)d_in[19]};
    const float* i2o_b[4] = {(const float*)d_in[14], (const float*)d_in[16], (const float*)d_in[18], (const float*)d_in[20]};
    const float* ri_w[4]  = {(const float*)d_in[21], (const float*)d_in[23], (const float*)d_in[25], (const float*)d_in[27]};
    const float* ri_b[4]  = {(const float*)d_in[22], (const float*)d_in[24], (const float*)d_in[26], (const float*)d_in[28]};
    const float* ro_w[4]  = {(const float*)d_in[29], (const float*)d_in[31], (const float*)d_in[33], (const float*)d_in[35]};
    const float* ro_b[4]  = {(const float*)d_in[30], (const float*)d_in[32], (const float*)d_in[34], (const float*)d_in[36]};
    const int* src_out  = (const int*)d_in[37];
    const int* dst_out  = (const int*)d_in[38];
    const int* src_in   = (const int*)d_in[39];
    const int* dst_in   = (const int*)d_in[40];

    unsigned* ws   = (unsigned*)d_ws;
    float*    nfi  = (float*)(ws + OFF_NFI);
    float*    f1s  = (float*)(ws + OFF_F1);
    unsigned* f2k  = ws + OFF_F2;
    unsigned* cnt  = ws + OFF_CNT;
    unsigned* ctro = ws + OFF_CTRO;
    unsigned* ctri = ws + OFF_CTRI;
    unsigned* lsto = ws + OFF_LISTO;
    unsigned* lsti = ws + OFF_LISTI;
    unsigned short* wts = (unsigned short*)(ws + OFF_WB);

    hipMemsetAsync(d_ws, 0, OFF_LISTO * sizeof(unsigned), stream);
    hipMemsetAsync((char*)d_out + (size_t)NIN * 64 * sizeof(float), 0,
                   (size_t)(NOUT_BASE - NIN) * 64 * sizeof(float), stream);

    WTab t;
    t.d[0]  = {o2i_w[0], 144,  64, 168,  64, OW_O2I0};
    t.d[1]  = {o2i_w[1],  64,  64,  72,  64, OW_O2I1};
    t.d[2]  = {o2i_w[2],  64,  64,  72,  64, OW_O2I2};
    t.d[3]  = {o2i_w[3],  64,  64,  72,  64, OW_O2I3};
    t.d[4]  = {o2i_w[4],  64, 128,  72, 128, OW_O2I4};
    t.d[5]  = {i2o_w[0], 144,  64, 168,  64, OW_I2O0};
    t.d[6]  = {i2o_w[1],  64,  64,  72,  64, OW_I2O1};
    t.d[7]  = {i2o_w[2],  64,  64,  72,  64, OW_I2O2};
    t.d[8]  = {i2o_w[3],  64,  65,  72,  80, OW_I2O3};
    t.d[9]  = {ri_w[0],  192,  64, 200,  64, OW_RI0};
    t.d[10] = {ri_w[1],   64,  64,  72,  64, OW_RI1};
    t.d[11] = {ri_w[2],   64,  64,  72,  64, OW_RI2};
    t.d[12] = {ri_w[3],   64,  64,  72,  64, OW_RI3};
    t.d[13] = {ro_w[0],  128,  64, 136,  64, OW_RO0};
    t.d[14] = {ro_w[1],   64,  64,  72,  64, OW_RO1};
    t.d[15] = {ro_w[2],   64,  64,  72,  64, OW_RO2};
    t.d[16] = {ro_w[3],   64,  64,  72,  64, OW_RO3};
    convert_w<<<dim3(50, 17), THREADS, 0, stream>>>(t, wts);

    compact_k<<<N_EDGES / THREADS, THREADS, 0, stream>>>(
        dst_out, dst_in, ctro, ctri, lsto, lsti);

    edge_out_mfma<<<(N_EDGES + 127) / 128, THREADS, 0, stream>>>(
        nf, ef_out, src_out, dst_out, lsto, ctro, wts,
        o2i_b[0], o2i_b[1], o2i_b[2], o2i_b[3], o2i_b[4], nfi);

    edge_in_mfma<<<(N_EDGES + 127) / 128, THREADS, 0, stream>>>(
        nf, ef_in, src_in, dst_in, lsti, ctri, wts,
        i2o_b[0], i2o_b[1], i2o_b[2], i2o_b[3], f1s, f2k, cnt);

    node_ri_mfma<<<NIN / 64, THREADS, 0, stream>>>(
        nf, nfi, wts, ri_b[0], ri_b[1], ri_b[2], ri_b[3], (float*)d_out);

    node_ro_mfma<<<NOUT / 64, THREADS, 0, stream>>>(
        nf, f1s, f2k, cnt, wts, ro_b[0], ro_b[1], ro_b[2], ro_b[3], (float*)d_out);
}

// Round 5
// 441.461 us; speedup vs baseline: 8.3223x; 1.6203x over previous
//
#include <hip/hip_runtime.h>
#include <cmath>

#define THREADS 256

static constexpr int N_NODES   = 100000;
static constexpr int N_EDGES   = 800000;
static constexpr int NIN       = 40000;   // input_mask: n < NIN
static constexpr int NOUT_BASE = 60000;   // output_mask: n >= NOUT_BASE
static constexpr int NOUT      = 40000;

static constexpr int CBLK = 1024;                                  // edges per compaction block
static constexpr int NBLK = (N_EDGES + CBLK - 1) / CBLK;           // 782

// ---- workspace layout (32-bit words) ----
static constexpr size_t OFF_NFI   = 0;                                // 40000*128 f32
static constexpr size_t OFF_F1    = OFF_NFI  + (size_t)NIN  * 128;    // 40000*32  f32
static constexpr size_t OFF_F2    = OFF_F1   + (size_t)NOUT * 32;     // 40000*32  u32 (keys)
static constexpr size_t OFF_CNT   = OFF_F2   + (size_t)NOUT * 32;     // 40000 u32
static constexpr size_t OFF_CTRO  = OFF_CNT  + NOUT;                  // 1 u32
static constexpr size_t OFF_CTRI  = OFF_CTRO + 1;                     // 1 u32
static constexpr size_t OFF_LISTO = OFF_CTRI + 1;                     // E u32
static constexpr size_t OFF_LISTI = OFF_LISTO + N_EDGES;              // E u32
static constexpr size_t OFF_WB    = OFF_LISTI + N_EDGES;              // bf16 weights region (108672 ushorts)
static constexpr size_t OFF_BCO   = OFF_WB + 54336;                   // NBLK u32 block counts/offsets (list O)
static constexpr size_t OFF_BCI   = OFF_BCO + 1024;                   // NBLK u32 (list I)

// converted-weight offsets (ushort units). [n][k] layout, strides = Kp+8 (bank pad)
static constexpr unsigned OW_O2I0 = 0;       // 64 x 168
static constexpr unsigned OW_O2I1 = 10752;   // 64 x 72
static constexpr unsigned OW_O2I2 = 15360;
static constexpr unsigned OW_O2I3 = 19968;
static constexpr unsigned OW_O2I4 = 24576;   // 128 x 72
static constexpr unsigned OW_I2O0 = 33792;   // 64 x 168
static constexpr unsigned OW_I2O1 = 44544;
static constexpr unsigned OW_I2O2 = 49152;
static constexpr unsigned OW_I2O3 = 53760;   // 80 x 72 (N=65 padded)
static constexpr unsigned OW_RI0  = 59520;   // 64 x 200
static constexpr unsigned OW_RI1  = 72320;
static constexpr unsigned OW_RI2  = 76928;
static constexpr unsigned OW_RI3  = 81536;
static constexpr unsigned OW_RO0  = 86144;   // 64 x 136
static constexpr unsigned OW_RO1  = 94848;
static constexpr unsigned OW_RO2  = 99456;
static constexpr unsigned OW_RO3  = 104064;  // end 108672

typedef __attribute__((ext_vector_type(8))) short short8;
typedef __attribute__((ext_vector_type(4))) float f32x4;

__device__ __forceinline__ float lrelu(float x) { return x > 0.0f ? x : 0.2f * x; }

__device__ __forceinline__ unsigned short f2b(float f) {   // RNE f32->bf16
    unsigned u = __float_as_uint(f);
    return (unsigned short)((u + 0x7fffu + ((u >> 16) & 1u)) >> 16);
}
__device__ __forceinline__ unsigned fkey(float f) {
    unsigned u = __float_as_uint(f);
    return (u & 0x80000000u) ? ~u : (u | 0x80000000u);
}
__device__ __forceinline__ float funkey(unsigned k) {
    return (k & 0x80000000u) ? __uint_as_float(k & 0x7fffffffu) : __uint_as_float(~k);
}

// copy n ushorts (n % 8 == 0, 16B aligned) global -> LDS
__device__ __forceinline__ void stage_w(unsigned short* dst, const unsigned short* src, int n, int tid) {
    for (int i = tid * 8; i < n; i += THREADS * 8)
        *(uint4*)(dst + i) = *(const uint4*)(src + i);
}

// One dense layer tile: MT m-tiles (16 rows each) per wave, NT n-tiles, KT k-steps of 32.
template<int MT, int NT, int KT, int XSTR, int WSTR>
__device__ __forceinline__ void gemm_core(const unsigned short* X, const unsigned short* W,
                                          const float* bias, int biasN, int wv, int lane,
                                          f32x4 (&acc)[MT][NT]) {
    const int r = lane & 15, kg = lane >> 4;
    short8 a[MT][KT];
#pragma unroll
    for (int mt = 0; mt < MT; ++mt)
#pragma unroll
        for (int kk = 0; kk < KT; ++kk)
            a[mt][kk] = *(const short8*)(X + (wv * 16 * MT + mt * 16 + r) * XSTR + kk * 32 + kg * 8);
#pragma unroll
    for (int nt = 0; nt < NT; ++nt) {
        const int c = nt * 16 + r;
        const float bv = (c < biasN) ? bias[c] : 0.0f;
#pragma unroll
        for (int mt = 0; mt < MT; ++mt) acc[mt][nt] = (f32x4){bv, bv, bv, bv};
    }
#pragma unroll
    for (int kk = 0; kk < KT; ++kk)
#pragma unroll
        for (int nt = 0; nt < NT; ++nt) {
            short8 b = *(const short8*)(W + (nt * 16 + r) * WSTR + kk * 32 + kg * 8);
#pragma unroll
            for (int mt = 0; mt < MT; ++mt)
                acc[mt][nt] = __builtin_amdgcn_mfma_f32_16x16x32_bf16(a[mt][kk], b, acc[mt][nt], 0, 0, 0);
        }
}

// leaky-relu + bf16 + in-place writeback to X (each wave touches only its own rows)
template<int MT, int NT, int XSTR>
__device__ __forceinline__ void writeback(unsigned short* X, f32x4 (&acc)[MT][NT], int wv, int lane) {
    const int r = lane & 15, kg = lane >> 4;
#pragma unroll
    for (int mt = 0; mt < MT; ++mt)
#pragma unroll
        for (int nt = 0; nt < NT; ++nt)
#pragma unroll
            for (int q = 0; q < 4; ++q)
                X[(wv * 16 * MT + mt * 16 + kg * 4 + q) * XSTR + nt * 16 + r] = f2b(lrelu(acc[mt][nt][q]));
}

// ---- weight conversion: f32 [K][N] -> bf16 [Np][stride] transposed, zero-padded ----
struct WDesc { const float* w; int K, N, stride, Np; unsigned off; };
struct WTab { WDesc d[17]; };

__global__ __launch_bounds__(THREADS)
void convert_w(WTab t, unsigned short* wts) {
    const WDesc d = t.d[blockIdx.y];
    const int idx = blockIdx.x * THREADS + threadIdx.x;
    const int tot = d.Np * d.stride;
    if (idx >= tot) return;
    const int n = idx / d.stride, k = idx - n * d.stride;
    const float v = (k < d.K && n < d.N) ? d.w[(size_t)k * d.N + n] : 0.0f;
    wts[d.off + idx] = f2b(v);
}

// ---- compaction phase 1: per-block survivor counts (no global atomics) ----
__global__ __launch_bounds__(THREADS)
void count_k(const int* __restrict__ dst_out, const int* __restrict__ dst_in,
             unsigned* __restrict__ bco, unsigned* __restrict__ bci) {
    const int base = blockIdx.x * CBLK;
    const int tid = threadIdx.x, lane = tid & 63, wv = tid >> 6;
    __shared__ unsigned so[4], si[4];
    unsigned co = 0, ci = 0;
#pragma unroll
    for (int it = 0; it < CBLK / THREADS; ++it) {
        const int e = base + it * THREADS + tid;
        const bool po = (e < N_EDGES) && (dst_out[e] < NIN);
        const bool pi = (e < N_EDGES) && (dst_in[e] >= NOUT_BASE);
        const unsigned long long mo = __ballot(po), mi = __ballot(pi);
        if (lane == 0) { co += (unsigned)__popcll(mo); ci += (unsigned)__popcll(mi); }
    }
    if (lane == 0) { so[wv] = co; si[wv] = ci; }
    __syncthreads();
    if (tid == 0) {
        bco[blockIdx.x] = so[0] + so[1] + so[2] + so[3];
        bci[blockIdx.x] = si[0] + si[1] + si[2] + si[3];
    }
}

// ---- compaction phase 2: exclusive scan of block counts (1 block; wave0=O, wave1=I) ----
__global__ __launch_bounds__(128)
void scan_k(unsigned* __restrict__ bco, unsigned* __restrict__ bci,
            unsigned* __restrict__ ctro, unsigned* __restrict__ ctri) {
    const int lane = threadIdx.x & 63;
    unsigned* arr = (threadIdx.x < 64) ? bco : bci;
    unsigned* tot = (threadIdx.x < 64) ? ctro : ctri;
    const int per = (NBLK + 63) / 64;
    const int lo = lane * per;
    const int hi = (lo + per < NBLK) ? lo + per : NBLK;
    unsigned s = 0;
    for (int i = lo; i < hi; ++i) s += arr[i];
    unsigned incl = s;
    for (int d = 1; d < 64; d <<= 1) {          // inclusive wave scan
        unsigned v = __shfl_up(incl, d);
        if (lane >= d) incl += v;
    }
    unsigned run = incl - s;                     // exclusive base for this lane's chunk
    for (int i = lo; i < hi; ++i) { const unsigned c = arr[i]; arr[i] = run; run += c; }
    if (lane == 63) *tot = incl;                 // grand total
}

// ---- compaction phase 3: emit survivors at scanned offsets (LDS-local base only) ----
__global__ __launch_bounds__(THREADS)
void emit_k(const int* __restrict__ dst_out, const int* __restrict__ dst_in,
            const unsigned* __restrict__ bco, const unsigned* __restrict__ bci,
            unsigned* __restrict__ listo, unsigned* __restrict__ listi) {
    const int base = blockIdx.x * CBLK;
    const int tid = threadIdx.x, lane = tid & 63;
    const unsigned long long lm = (1ull << lane) - 1ull;
    __shared__ unsigned lco, lci;
    if (tid == 0) { lco = bco[blockIdx.x]; lci = bci[blockIdx.x]; }
    __syncthreads();
#pragma unroll
    for (int it = 0; it < CBLK / THREADS; ++it) {
        const int e = base + it * THREADS + tid;
        const bool po = (e < N_EDGES) && (dst_out[e] < NIN);
        const bool pi = (e < N_EDGES) && (dst_in[e] >= NOUT_BASE);
        const unsigned long long mo = __ballot(po), mi = __ballot(pi);
        unsigned bo = 0, bi = 0;
        if (lane == 0) {
            bo = atomicAdd(&lco, (unsigned)__popcll(mo));   // LDS atomic
            bi = atomicAdd(&lci, (unsigned)__popcll(mi));
        }
        bo = (unsigned)__shfl((int)bo, 0);
        bi = (unsigned)__shfl((int)bi, 0);
        if (po) listo[bo + (unsigned)__popcll(mo & lm)] = (unsigned)e;
        if (pi) listi[bi + (unsigned)__popcll(mi & lm)] = (unsigned)e;
    }
}

// stage [nf[src] | nf[dst] | ef] -> bf16 X rows (21 chunks of 8 cols, pad 144..167 = 0)
__device__ __forceinline__ void stage_edge_x(unsigned short* X, const float* nf, const float* ef,
                                             const int* s_eid, const int* s_src, const int* s_dst, int tid) {
    for (int i = tid; i < 128 * 21; i += THREADS) {
        const int el = i / 21, q = i - el * 21;
        unsigned p0 = 0, p1 = 0, p2 = 0, p3 = 0;
        if (s_eid[el] >= 0 && q < 18) {
            const float* sp;
            if (q < 8)       sp = nf + (size_t)s_src[el] * 64 + q * 8;
            else if (q < 16) sp = nf + (size_t)s_dst[el] * 64 + (q - 8) * 8;
            else             sp = ef + (size_t)s_eid[el] * 16 + (q - 16) * 8;
            const float4 va = *(const float4*)sp, vb = *(const float4*)(sp + 4);
            p0 = f2b(va.x) | ((unsigned)f2b(va.y) << 16);
            p1 = f2b(va.z) | ((unsigned)f2b(va.w) << 16);
            p2 = f2b(vb.x) | ((unsigned)f2b(vb.y) << 16);
            p3 = f2b(vb.z) | ((unsigned)f2b(vb.w) << 16);
        }
        *(uint4*)(X + el * 168 + q * 8) = make_uint4(p0, p1, p2, p3);
    }
}

// ---- o2i edge MLP (MFMA) + scatter-add ----
__global__ __launch_bounds__(THREADS)
void edge_out_mfma(const float* __restrict__ nf, const float* __restrict__ ef,
                   const int* __restrict__ src, const int* __restrict__ dst,
                   const unsigned* __restrict__ list, const unsigned* __restrict__ counter,
                   const unsigned short* __restrict__ wts,
                   const float* __restrict__ b0, const float* __restrict__ b1,
                   const float* __restrict__ b2, const float* __restrict__ b3,
                   const float* __restrict__ b4, float* __restrict__ nfi) {
    __shared__ unsigned short X[128 * 168];
    __shared__ unsigned short Wl[10752];
    __shared__ int s_eid[128], s_src[128], s_dst[128];
    const unsigned total = *counter;
    const unsigned base  = (unsigned)blockIdx.x * 128u;
    if (base >= total) return;
    const int tid = threadIdx.x, lane = tid & 63, wv = tid >> 6;
    if (tid < 128) {
        const unsigned idx = base + (unsigned)tid;
        const int e = (idx < total) ? (int)list[idx] : -1;
        s_eid[tid] = e; s_src[tid] = e >= 0 ? src[e] : 0; s_dst[tid] = e >= 0 ? dst[e] : 0;
    }
    __syncthreads();
    stage_edge_x(X, nf, ef, s_eid, s_src, s_dst, tid);
    stage_w(Wl, wts + OW_O2I0, 10752, tid);
    __syncthreads();
    f32x4 acc[2][4];
    gemm_core<2, 4, 5, 168, 168>(X, Wl, b0, 64, wv, lane, acc);
    writeback<2, 4, 168>(X, acc, wv, lane);
    __syncthreads(); stage_w(Wl, wts + OW_O2I1, 4608, tid); __syncthreads();
    gemm_core<2, 4, 2, 168, 72>(X, Wl, b1, 64, wv, lane, acc);
    writeback<2, 4, 168>(X, acc, wv, lane);
    __syncthreads(); stage_w(Wl, wts + OW_O2I2, 4608, tid); __syncthreads();
    gemm_core<2, 4, 2, 168, 72>(X, Wl, b2, 64, wv, lane, acc);
    writeback<2, 4, 168>(X, acc, wv, lane);
    __syncthreads(); stage_w(Wl, wts + OW_O2I3, 4608, tid); __syncthreads();
    gemm_core<2, 4, 2, 168, 72>(X, Wl, b3, 64, wv, lane, acc);
    writeback<2, 4, 168>(X, acc, wv, lane);
    __syncthreads(); stage_w(Wl, wts + OW_O2I4, 9216, tid); __syncthreads();
    f32x4 acc8[2][8];
    gemm_core<2, 8, 2, 168, 72>(X, Wl, b4, 128, wv, lane, acc8);
    const int r = lane & 15, kg = lane >> 4;
#pragma unroll
    for (int mt = 0; mt < 2; ++mt)
#pragma unroll
        for (int q = 0; q < 4; ++q) {
            const int row = wv * 32 + mt * 16 + kg * 4 + q;
            if (s_eid[row] < 0) continue;
            float* p = nfi + (size_t)s_dst[row] * 128;
#pragma unroll
            for (int nt = 0; nt < 8; ++nt) atomicAdd(p + nt * 16 + r, acc8[mt][nt][q]);
        }
}

// ---- i2o edge MLP (MFMA) + gate + mean/max scatter ----
__global__ __launch_bounds__(THREADS)
void edge_in_mfma(const float* __restrict__ nf, const float* __restrict__ ef,
                  const int* __restrict__ src, const int* __restrict__ dst,
                  const unsigned* __restrict__ list, const unsigned* __restrict__ counter,
                  const unsigned short* __restrict__ wts,
                  const float* __restrict__ b0, const float* __restrict__ b1,
                  const float* __restrict__ b2, const float* __restrict__ b3,
                  float* __restrict__ f1s, unsigned* __restrict__ f2k, unsigned* __restrict__ cnt) {
    __shared__ unsigned short X[128 * 168];
    __shared__ unsigned short Wl[10752];
    __shared__ int s_eid[128], s_src[128], s_dst[128];
    __shared__ float g[128];
    const unsigned total = *counter;
    const unsigned base  = (unsigned)blockIdx.x * 128u;
    if (base >= total) return;
    const int tid = threadIdx.x, lane = tid & 63, wv = tid >> 6;
    if (tid < 128) {
        const unsigned idx = base + (unsigned)tid;
        const int e = (idx < total) ? (int)list[idx] : -1;
        s_eid[tid] = e; s_src[tid] = e >= 0 ? src[e] : 0; s_dst[tid] = e >= 0 ? dst[e] : 0;
    }
    __syncthreads();
    stage_edge_x(X, nf, ef, s_eid, s_src, s_dst, tid);
    stage_w(Wl, wts + OW_I2O0, 10752, tid);
    __syncthreads();
    f32x4 acc[2][4];
    gemm_core<2, 4, 5, 168, 168>(X, Wl, b0, 64, wv, lane, acc);
    writeback<2, 4, 168>(X, acc, wv, lane);
    __syncthreads(); stage_w(Wl, wts + OW_I2O1, 4608, tid); __syncthreads();
    gemm_core<2, 4, 2, 168, 72>(X, Wl, b1, 64, wv, lane, acc);
    writeback<2, 4, 168>(X, acc, wv, lane);
    __syncthreads(); stage_w(Wl, wts + OW_I2O2, 4608, tid); __syncthreads();
    gemm_core<2, 4, 2, 168, 72>(X, Wl, b2, 64, wv, lane, acc);
    writeback<2, 4, 168>(X, acc, wv, lane);
    __syncthreads(); stage_w(Wl, wts + OW_I2O3, 5760, tid); __syncthreads();
    f32x4 acc5[2][5];
    gemm_core<2, 5, 2, 168, 72>(X, Wl, b3, 65, wv, lane, acc5);
    const int r = lane & 15, kg = lane >> 4;
    if (r == 0) {
#pragma unroll
        for (int mt = 0; mt < 2; ++mt)
#pragma unroll
            for (int q = 0; q < 4; ++q) g[wv * 32 + mt * 16 + kg * 4 + q] = acc5[mt][4][q];
    }
    __syncthreads();
#pragma unroll
    for (int mt = 0; mt < 2; ++mt)
#pragma unroll
        for (int q = 0; q < 4; ++q) {
            const int row = wv * 32 + mt * 16 + kg * 4 + q;
            if (s_eid[row] < 0) continue;
            const float kgv = 1.0f / (1.0f + expf(-g[row]));
            const int rr = s_dst[row] - NOUT_BASE;
#pragma unroll
            for (int nt = 0; nt < 5; ++nt) {
                const int c = nt * 16 + r;
                if (c == 0 || c > 64) continue;
                const float v = acc5[mt][nt][q] * kgv;
                if (c <= 32) atomicAdd(f1s + (size_t)rr * 32 + (c - 1), v);
                else         atomicMax(f2k + (size_t)rr * 32 + (c - 33), fkey(v));
            }
            if (r == 0) atomicAdd(cnt + rr, 1u);
        }
}

// ---- ri node MLP (192->64->64->64->64), nodes [0, NIN) ----
__global__ __launch_bounds__(THREADS)
void node_ri_mfma(const float* __restrict__ nf, const float* __restrict__ nfi,
                  const unsigned short* __restrict__ wts,
                  const float* __restrict__ b0, const float* __restrict__ b1,
                  const float* __restrict__ b2, const float* __restrict__ b3,
                  float* __restrict__ out) {
    __shared__ unsigned short X[64 * 200];
    __shared__ unsigned short Wl[12800];
    const int tid = threadIdx.x, lane = tid & 63, wv = tid >> 6;
    const int base = blockIdx.x * 64;
    for (int i = tid; i < 64 * 25; i += THREADS) {
        const int el = i / 25, q = i - el * 25;
        unsigned p0 = 0, p1 = 0, p2 = 0, p3 = 0;
        if (q < 24) {
            const float* sp = (q < 8) ? nf + (size_t)(base + el) * 64 + q * 8
                                      : nfi + (size_t)(base + el) * 128 + (q - 8) * 8;
            const float4 va = *(const float4*)sp, vb = *(const float4*)(sp + 4);
            p0 = f2b(va.x) | ((unsigned)f2b(va.y) << 16);
            p1 = f2b(va.z) | ((unsigned)f2b(va.w) << 16);
            p2 = f2b(vb.x) | ((unsigned)f2b(vb.y) << 16);
            p3 = f2b(vb.z) | ((unsigned)f2b(vb.w) << 16);
        }
        *(uint4*)(X + el * 200 + q * 8) = make_uint4(p0, p1, p2, p3);
    }
    stage_w(Wl, wts + OW_RI0, 12800, tid);
    __syncthreads();
    f32x4 acc[1][4];
    gemm_core<1, 4, 6, 200, 200>(X, Wl, b0, 64, wv, lane, acc);
    writeback<1, 4, 200>(X, acc, wv, lane);
    __syncthreads(); stage_w(Wl, wts + OW_RI1, 4608, tid); __syncthreads();
    gemm_core<1, 4, 2, 200, 72>(X, Wl, b1, 64, wv, lane, acc);
    writeback<1, 4, 200>(X, acc, wv, lane);
    __syncthreads(); stage_w(Wl, wts + OW_RI2, 4608, tid); __syncthreads();
    gemm_core<1, 4, 2, 200, 72>(X, Wl, b2, 64, wv, lane, acc);
    writeback<1, 4, 200>(X, acc, wv, lane);
    __syncthreads(); stage_w(Wl, wts + OW_RI3, 4608, tid); __syncthreads();
    gemm_core<1, 4, 2, 200, 72>(X, Wl, b3, 64, wv, lane, acc);
    const int r = lane & 15, kg = lane >> 4;
#pragma unroll
    for (int nt = 0; nt < 4; ++nt)
#pragma unroll
        for (int q = 0; q < 4; ++q)
            out[(size_t)(base + wv * 16 + kg * 4 + q) * 64 + nt * 16 + r] = acc[0][nt][q];
}

// ---- ro node MLP (128->64->64->64->64), nodes [NOUT_BASE, N) ----
__global__ __launch_bounds__(THREADS)
void node_ro_mfma(const float* __restrict__ nf, const float* __restrict__ f1s,
                  const unsigned* __restrict__ f2k, const unsigned* __restrict__ cnt,
                  const unsigned short* __restrict__ wts,
                  const float* __restrict__ b0, const float* __restrict__ b1,
                  const float* __restrict__ b2, const float* __restrict__ b3,
                  float* __restrict__ out) {
    __shared__ unsigned short X[64 * 136];
    __shared__ unsigned short Wl[8704];
    const int tid = threadIdx.x, lane = tid & 63, wv = tid >> 6;
    const int rbase = blockIdx.x * 64;           // node = NOUT_BASE + rbase + el
    for (int i = tid; i < 64 * 17; i += THREADS) {
        const int el = i / 17, q = i - el * 17;
        const int rr = rbase + el;
        unsigned p0 = 0, p1 = 0, p2 = 0, p3 = 0;
        if (q < 16) {
            float v[8];
            if (q < 8) {
                const float* sp = nf + (size_t)(NOUT_BASE + rr) * 64 + q * 8;
                const float4 va = *(const float4*)sp, vb = *(const float4*)(sp + 4);
                v[0]=va.x; v[1]=va.y; v[2]=va.z; v[3]=va.w; v[4]=vb.x; v[5]=vb.y; v[6]=vb.z; v[7]=vb.w;
            } else {
                const unsigned cc = cnt[rr];
                if (q < 12) {
                    const float inv = 1.0f / fmaxf((float)cc, 1.0f);
#pragma unroll
                    for (int j = 0; j < 8; ++j) v[j] = f1s[(size_t)rr * 32 + (q - 8) * 8 + j] * inv;
                } else {
#pragma unroll
                    for (int j = 0; j < 8; ++j)
                        v[j] = (cc > 0u) ? funkey(f2k[(size_t)rr * 32 + (q - 12) * 8 + j]) : 0.0f;
                }
            }
            p0 = f2b(v[0]) | ((unsigned)f2b(v[1]) << 16);
            p1 = f2b(v[2]) | ((unsigned)f2b(v[3]) << 16);
            p2 = f2b(v[4]) | ((unsigned)f2b(v[5]) << 16);
            p3 = f2b(v[6]) | ((unsigned)f2b(v[7]) << 16);
        }
        *(uint4*)(X + el * 136 + q * 8) = make_uint4(p0, p1, p2, p3);
    }
    stage_w(Wl, wts + OW_RO0, 8704, tid);
    __syncthreads();
    f32x4 acc[1][4];
    gemm_core<1, 4, 4, 136, 136>(X, Wl, b0, 64, wv, lane, acc);
    writeback<1, 4, 136>(X, acc, wv, lane);
    __syncthreads(); stage_w(Wl, wts + OW_RO1, 4608, tid); __syncthreads();
    gemm_core<1, 4, 2, 136, 72>(X, Wl, b1, 64, wv, lane, acc);
    writeback<1, 4, 136>(X, acc, wv, lane);
    __syncthreads(); stage_w(Wl, wts + OW_RO2, 4608, tid); __syncthreads();
    gemm_core<1, 4, 2, 136, 72>(X, Wl, b2, 64, wv, lane, acc);
    writeback<1, 4, 136>(X, acc, wv, lane);
    __syncthreads(); stage_w(Wl, wts + OW_RO3, 4608, tid); __syncthreads();
    gemm_core<1, 4, 2, 136, 72>(X, Wl, b3, 64, wv, lane, acc);
    const int r = lane & 15, kg = lane >> 4;
#pragma unroll
    for (int nt = 0; nt < 4; ++nt)
#pragma unroll
        for (int q = 0; q < 4; ++q)
            out[(size_t)(NOUT_BASE + rbase + wv * 16 + kg * 4 + q) * 64 + nt * 16 + r] = acc[0][nt][q];
}

extern "C" void kernel_launch(void* const* d_in, const int* in_sizes, int n_in,
                              void* d_out, int out_size, void* d_ws, size_t ws_size,
                              hipStream_t stream) {
    const float* nf     = (const float*)d_in[0];
    const float* ef_out = (const float*)d_in[1];
    const float* ef_in  = (const float*)d_in[2];
    const float* o2i_w[5] = {(const float*)d_in[3], (const float*)d_in[5], (const float*)d_in[7], (const float*)d_in[9], (const float*)d_in[11]};
    const float* o2i_b[5] = {(const float*)d_in[4], (const float*)d_in[6], (const float*)d_in[8], (const float*)d_in[10], (const float*)d_in[12]};
    const float* i2o_w[4] = {(const float*)d_in[13], (const float*)d_in[15], (const float*)d_in[17], (const float*)d_in[19]};
    const float* i2o_b[4] = {(const float*)d_in[14], (const float*)d_in[16], (const float*)d_in[18], (const float*)d_in[20]};
    const float* ri_w[4]  = {(const float*)d_in[21], (const float*)d_in[23], (const float*)d_in[25], (const float*)d_in[27]};
    const float* ri_b[4]  = {(const float*)d_in[22], (const float*)d_in[24], (const float*)d_in[26], (const float*)d_in[28]};
    const float* ro_w[4]  = {(const float*)d_in[29], (const float*)d_in[31], (const float*)d_in[33], (const float*)d_in[35]};
    const float* ro_b[4]  = {(const float*)d_in[30], (const float*)d_in[32], (const float*)d_in[34], (const float*)d_in[36]};
    const int* src_out  = (const int*)d_in[37];
    const int* dst_out  = (const int*)d_in[38];
    const int* src_in   = (const int*)d_in[39];
    const int* dst_in   = (const int*)d_in[40];

    unsigned* ws   = (unsigned*)d_ws;
    float*    nfi  = (float*)(ws + OFF_NFI);
    float*    f1s  = (float*)(ws + OFF_F1);
    unsigned* f2k  = ws + OFF_F2;
    unsigned* cnt  = ws + OFF_CNT;
    unsigned* ctro = ws + OFF_CTRO;
    unsigned* ctri = ws + OFF_CTRI;
    unsigned* lsto = ws + OFF_LISTO;
    unsigned* lsti = ws + OFF_LISTI;
    unsigned short* wts = (unsigned short*)(ws + OFF_WB);
    unsigned* bco  = ws + OFF_BCO;
    unsigned* bci  = ws + OFF_BCI;

    hipMemsetAsync(d_ws, 0, OFF_LISTO * sizeof(unsigned), stream);
    hipMemsetAsync((char*)d_out + (size_t)NIN * 64 * sizeof(float), 0,
                   (size_t)(NOUT_BASE - NIN) * 64 * sizeof(float), stream);

    WTab t;
    t.d[0]  = {o2i_w[0], 144,  64, 168,  64, OW_O2I0};
    t.d[1]  = {o2i_w[1],  64,  64,  72,  64, OW_O2I1};
    t.d[2]  = {o2i_w[2],  64,  64,  72,  64, OW_O2I2};
    t.d[3]  = {o2i_w[3],  64,  64,  72,  64, OW_O2I3};
    t.d[4]  = {o2i_w[4],  64, 128,  72, 128, OW_O2I4};
    t.d[5]  = {i2o_w[0], 144,  64, 168,  64, OW_I2O0};
    t.d[6]  = {i2o_w[1],  64,  64,  72,  64, OW_I2O1};
    t.d[7]  = {i2o_w[2],  64,  64,  72,  64, OW_I2O2};
    t.d[8]  = {i2o_w[3],  64,  65,  72,  80, OW_I2O3};
    t.d[9]  = {ri_w[0],  192,  64, 200,  64, OW_RI0};
    t.d[10] = {ri_w[1],   64,  64,  72,  64, OW_RI1};
    t.d[11] = {ri_w[2],   64,  64,  72,  64, OW_RI2};
    t.d[12] = {ri_w[3],   64,  64,  72,  64, OW_RI3};
    t.d[13] = {ro_w[0],  128,  64, 136,  64, OW_RO0};
    t.d[14] = {ro_w[1],   64,  64,  72,  64, OW_RO1};
    t.d[15] = {ro_w[2],   64,  64,  72,  64, OW_RO2};
    t.d[16] = {ro_w[3],   64,  64,  72,  64, OW_RO3};
    convert_w<<<dim3(50, 17), THREADS, 0, stream>>>(t, wts);

    count_k<<<NBLK, THREADS, 0, stream>>>(dst_out, dst_in, bco, bci);
    scan_k<<<1, 128, 0, stream>>>(bco, bci, ctro, ctri);
    emit_k<<<NBLK, THREADS, 0, stream>>>(dst_out, dst_in, bco, bci, lsto, lsti);

    edge_out_mfma<<<(N_EDGES + 127) / 128, THREADS, 0, stream>>>(
        nf, ef_out, src_out, dst_out, lsto, ctro, wts,
        o2i_b[0], o2i_b[1], o2i_b[2], o2i_b[3], o2i_b[4], nfi);

    edge_in_mfma<<<(N_EDGES + 127) / 128, THREADS, 0, stream>>>(
        nf, ef_in, src_in, dst_in, lsti, ctri, wts,
        i2o_b[0], i2o_b[1], i2o_b[2], i2o_b[3], f1s, f2k, cnt);

    node_ri_mfma<<<NIN / 64, THREADS, 0, stream>>>(
        nf, nfi, wts, ri_b[0], ri_b[1], ri_b[2], ri_b[3], (float*)d_out);

    node_ro_mfma<<<NOUT / 64, THREADS, 0, stream>>>(
        nf, f1s, f2k, cnt, wts, ro_b[0], ro_b[1], ro_b[2], ro_b[3], (float*)d_out);
}

// Round 6
// 413.055 us; speedup vs baseline: 8.8946x; 1.0688x over previous
//
#include <hip/hip_runtime.h>
#include <cmath>

#define THREADS 256

static constexpr int N_NODES   = 100000;
static constexpr int N_EDGES   = 800000;
static constexpr int NIN       = 40000;   // input_mask: n < NIN
static constexpr int NOUT_BASE = 60000;   // output_mask: n >= NOUT_BASE
static constexpr int NOUT      = 40000;

static constexpr int CBLK = 1024;                                  // edges per compaction block
static constexpr int NBLK = (N_EDGES + CBLK - 1) / CBLK;           // 782

// ---- workspace layout (32-bit words) ----
static constexpr size_t OFF_NFI   = 0;                                // 40000*128 f32
static constexpr size_t OFF_F1    = OFF_NFI  + (size_t)NIN  * 128;    // 40000*32  f32
static constexpr size_t OFF_F2    = OFF_F1   + (size_t)NOUT * 32;     // 40000*32  u32 (keys)
static constexpr size_t OFF_CNT   = OFF_F2   + (size_t)NOUT * 32;     // 40000 u32
static constexpr size_t OFF_CTRO  = OFF_CNT  + NOUT;                  // 1 u32
static constexpr size_t OFF_CTRI  = OFF_CTRO + 1;                     // 1 u32
static constexpr size_t OFF_LISTO = OFF_CTRI + 1;                     // E u32
static constexpr size_t OFF_LISTI = OFF_LISTO + N_EDGES;              // E u32
static constexpr size_t OFF_WB    = OFF_LISTI + N_EDGES;              // bf16 weights region (108672 ushorts)
static constexpr size_t OFF_BCO   = OFF_WB + 54336;                   // NBLK u32 block counts/offsets (list O)
static constexpr size_t OFF_BCI   = OFF_BCO + 1024;                   // NBLK u32 (list I)

// converted-weight offsets (ushort units). [n][k] layout, strides = Kp+8 (bank pad)
static constexpr unsigned OW_O2I0 = 0;       // 64 x 168
static constexpr unsigned OW_O2I1 = 10752;   // 64 x 72
static constexpr unsigned OW_O2I2 = 15360;
static constexpr unsigned OW_O2I3 = 19968;
static constexpr unsigned OW_O2I4 = 24576;   // 128 x 72   (o2i total 33792)
static constexpr unsigned OW_I2O0 = 33792;   // 64 x 168
static constexpr unsigned OW_I2O1 = 44544;
static constexpr unsigned OW_I2O2 = 49152;
static constexpr unsigned OW_I2O3 = 53760;   // 80 x 72 (N=65 padded)  (i2o total 25728)
static constexpr unsigned OW_RI0  = 59520;   // 64 x 200
static constexpr unsigned OW_RI1  = 72320;
static constexpr unsigned OW_RI2  = 76928;
static constexpr unsigned OW_RI3  = 81536;
static constexpr unsigned OW_RO0  = 86144;   // 64 x 136
static constexpr unsigned OW_RO1  = 94848;
static constexpr unsigned OW_RO2  = 99456;
static constexpr unsigned OW_RO3  = 104064;  // end 108672

typedef __attribute__((ext_vector_type(8))) short short8;
typedef __attribute__((ext_vector_type(4))) float f32x4;

__device__ __forceinline__ float lrelu(float x) { return x > 0.0f ? x : 0.2f * x; }

__device__ __forceinline__ unsigned short f2b(float f) {   // RNE f32->bf16
    unsigned u = __float_as_uint(f);
    return (unsigned short)((u + 0x7fffu + ((u >> 16) & 1u)) >> 16);
}
__device__ __forceinline__ unsigned pk2(float a, float b) {
    return (unsigned)f2b(a) | ((unsigned)f2b(b) << 16);
}
__device__ __forceinline__ unsigned fkey(float f) {
    unsigned u = __float_as_uint(f);
    return (u & 0x80000000u) ? ~u : (u | 0x80000000u);
}
__device__ __forceinline__ float funkey(unsigned k) {
    return (k & 0x80000000u) ? __uint_as_float(k & 0x7fffffffu) : __uint_as_float(~k);
}

// ---- block-cooperative gemm (node kernels): MT m-tiles per wave, via wave index wv ----
template<int MT, int NT, int KT, int XSTR, int WSTR>
__device__ __forceinline__ void gemm_core(const unsigned short* X, const unsigned short* W,
                                          const float* bias, int biasN, int wv, int lane,
                                          f32x4 (&acc)[MT][NT]) {
    const int r = lane & 15, kg = lane >> 4;
    short8 a[MT][KT];
#pragma unroll
    for (int mt = 0; mt < MT; ++mt)
#pragma unroll
        for (int kk = 0; kk < KT; ++kk)
            a[mt][kk] = *(const short8*)(X + (wv * 16 * MT + mt * 16 + r) * XSTR + kk * 32 + kg * 8);
#pragma unroll
    for (int nt = 0; nt < NT; ++nt) {
        const int c = nt * 16 + r;
        const float bv = (c < biasN) ? bias[c] : 0.0f;
#pragma unroll
        for (int mt = 0; mt < MT; ++mt) acc[mt][nt] = (f32x4){bv, bv, bv, bv};
    }
#pragma unroll
    for (int kk = 0; kk < KT; ++kk)
#pragma unroll
        for (int nt = 0; nt < NT; ++nt) {
            short8 b = *(const short8*)(W + (nt * 16 + r) * WSTR + kk * 32 + kg * 8);
#pragma unroll
            for (int mt = 0; mt < MT; ++mt)
                acc[mt][nt] = __builtin_amdgcn_mfma_f32_16x16x32_bf16(a[mt][kk], b, acc[mt][nt], 0, 0, 0);
        }
}

template<int MT, int NT, int XSTR>
__device__ __forceinline__ void writeback(unsigned short* X, f32x4 (&acc)[MT][NT], int wv, int lane) {
    const int r = lane & 15, kg = lane >> 4;
#pragma unroll
    for (int mt = 0; mt < MT; ++mt)
#pragma unroll
        for (int nt = 0; nt < NT; ++nt)
#pragma unroll
            for (int q = 0; q < 4; ++q)
                X[(wv * 16 * MT + mt * 16 + kg * 4 + q) * XSTR + nt * 16 + r] = f2b(lrelu(acc[mt][nt][q]));
}

// ---- wave-local gemm (edge kernels): Xw = this wave's 32-row region, bias in regs ----
template<int MT, int NT, int KT, int XSTR, int WSTR>
__device__ __forceinline__ void gemm_w(const unsigned short* Xw, const unsigned short* W,
                                       const float* bv, int lane, f32x4 (&acc)[MT][NT]) {
    const int r = lane & 15, kg = lane >> 4;
    short8 a[MT][KT];
#pragma unroll
    for (int mt = 0; mt < MT; ++mt)
#pragma unroll
        for (int kk = 0; kk < KT; ++kk)
            a[mt][kk] = *(const short8*)(Xw + (mt * 16 + r) * XSTR + kk * 32 + kg * 8);
#pragma unroll
    for (int nt = 0; nt < NT; ++nt)
#pragma unroll
        for (int mt = 0; mt < MT; ++mt) acc[mt][nt] = (f32x4){bv[nt], bv[nt], bv[nt], bv[nt]};
#pragma unroll
    for (int kk = 0; kk < KT; ++kk)
#pragma unroll
        for (int nt = 0; nt < NT; ++nt) {
            short8 b = *(const short8*)(W + (nt * 16 + r) * WSTR + kk * 32 + kg * 8);
#pragma unroll
            for (int mt = 0; mt < MT; ++mt)
                acc[mt][nt] = __builtin_amdgcn_mfma_f32_16x16x32_bf16(a[mt][kk], b, acc[mt][nt], 0, 0, 0);
        }
}

template<int MT, int NT, int XSTR>
__device__ __forceinline__ void writeback_w(unsigned short* Xw, f32x4 (&acc)[MT][NT], int lane) {
    const int r = lane & 15, kg = lane >> 4;
#pragma unroll
    for (int mt = 0; mt < MT; ++mt)
#pragma unroll
        for (int nt = 0; nt < NT; ++nt)
#pragma unroll
            for (int q = 0; q < 4; ++q)
                Xw[(mt * 16 + kg * 4 + q) * XSTR + nt * 16 + r] = f2b(lrelu(acc[mt][nt][q]));
}

// ---- weight conversion: f32 [K][N] -> bf16 [Np][stride] transposed, zero-padded ----
struct WDesc { const float* w; int K, N, stride, Np; unsigned off; };
struct WTab { WDesc d[17]; };

__global__ __launch_bounds__(THREADS)
void convert_w(WTab t, unsigned short* wts) {
    const WDesc d = t.d[blockIdx.y];
    const int idx = blockIdx.x * THREADS + threadIdx.x;
    const int tot = d.Np * d.stride;
    if (idx >= tot) return;
    const int n = idx / d.stride, k = idx - n * d.stride;
    const float v = (k < d.K && n < d.N) ? d.w[(size_t)k * d.N + n] : 0.0f;
    wts[d.off + idx] = f2b(v);
}

// ---- compaction phase 1: per-block survivor counts ----
__global__ __launch_bounds__(THREADS)
void count_k(const int* __restrict__ dst_out, const int* __restrict__ dst_in,
             unsigned* __restrict__ bco, unsigned* __restrict__ bci) {
    const int base = blockIdx.x * CBLK;
    const int tid = threadIdx.x, lane = tid & 63, wv = tid >> 6;
    __shared__ unsigned so[4], si[4];
    unsigned co = 0, ci = 0;
#pragma unroll
    for (int it = 0; it < CBLK / THREADS; ++it) {
        const int e = base + it * THREADS + tid;
        const bool po = (e < N_EDGES) && (dst_out[e] < NIN);
        const bool pi = (e < N_EDGES) && (dst_in[e] >= NOUT_BASE);
        const unsigned long long mo = __ballot(po), mi = __ballot(pi);
        if (lane == 0) { co += (unsigned)__popcll(mo); ci += (unsigned)__popcll(mi); }
    }
    if (lane == 0) { so[wv] = co; si[wv] = ci; }
    __syncthreads();
    if (tid == 0) {
        bco[blockIdx.x] = so[0] + so[1] + so[2] + so[3];
        bci[blockIdx.x] = si[0] + si[1] + si[2] + si[3];
    }
}

// ---- compaction phase 2: exclusive scan (1 block; wave0=O, wave1=I) ----
__global__ __launch_bounds__(128)
void scan_k(unsigned* __restrict__ bco, unsigned* __restrict__ bci,
            unsigned* __restrict__ ctro, unsigned* __restrict__ ctri) {
    const int lane = threadIdx.x & 63;
    unsigned* arr = (threadIdx.x < 64) ? bco : bci;
    unsigned* tot = (threadIdx.x < 64) ? ctro : ctri;
    const int per = (NBLK + 63) / 64;
    const int lo = lane * per;
    const int hi = (lo + per < NBLK) ? lo + per : NBLK;
    unsigned s = 0;
    for (int i = lo; i < hi; ++i) s += arr[i];
    unsigned incl = s;
    for (int d = 1; d < 64; d <<= 1) {
        unsigned v = __shfl_up(incl, d);
        if (lane >= d) incl += v;
    }
    unsigned run = incl - s;
    for (int i = lo; i < hi; ++i) { const unsigned c = arr[i]; arr[i] = run; run += c; }
    if (lane == 63) *tot = incl;
}

// ---- compaction phase 3: emit survivors ----
__global__ __launch_bounds__(THREADS)
void emit_k(const int* __restrict__ dst_out, const int* __restrict__ dst_in,
            const unsigned* __restrict__ bco, const unsigned* __restrict__ bci,
            unsigned* __restrict__ listo, unsigned* __restrict__ listi) {
    const int base = blockIdx.x * CBLK;
    const int tid = threadIdx.x, lane = tid & 63;
    const unsigned long long lm = (1ull << lane) - 1ull;
    __shared__ unsigned lco, lci;
    if (tid == 0) { lco = bco[blockIdx.x]; lci = bci[blockIdx.x]; }
    __syncthreads();
#pragma unroll
    for (int it = 0; it < CBLK / THREADS; ++it) {
        const int e = base + it * THREADS + tid;
        const bool po = (e < N_EDGES) && (dst_out[e] < NIN);
        const bool pi = (e < N_EDGES) && (dst_in[e] >= NOUT_BASE);
        const unsigned long long mo = __ballot(po), mi = __ballot(pi);
        unsigned bo = 0, bi = 0;
        if (lane == 0) {
            bo = atomicAdd(&lco, (unsigned)__popcll(mo));
            bi = atomicAdd(&lci, (unsigned)__popcll(mi));
        }
        bo = (unsigned)__shfl((int)bo, 0);
        bi = (unsigned)__shfl((int)bi, 0);
        if (po) listo[bo + (unsigned)__popcll(mo & lm)] = (unsigned)e;
        if (pi) listi[bi + (unsigned)__popcll(mi & lm)] = (unsigned)e;
    }
}

// ---- o2i edge MLP: persistent, all weights LDS-resident, barrier-free per-wave loop ----
__global__ __launch_bounds__(512)
void edge_out_mfma(const float* __restrict__ nf, const float* __restrict__ ef,
                   const int* __restrict__ src, const int* __restrict__ dst,
                   const unsigned* __restrict__ list, const unsigned* __restrict__ counter,
                   const unsigned short* __restrict__ wts,
                   const float* __restrict__ b0, const float* __restrict__ b1,
                   const float* __restrict__ b2, const float* __restrict__ b3,
                   const float* __restrict__ b4, float* __restrict__ nfi) {
    __shared__ unsigned short W[33792];      // all 5 o2i layers
    __shared__ unsigned short X[256 * 168];  // 8 waves x 32 rows
    const int tid = threadIdx.x, lane = tid & 63, wv = tid >> 6;
    const int r = lane & 15, kg = lane >> 4;
    for (int i = tid * 8; i < 33792; i += 512 * 8)
        *(uint4*)(W + i) = *(const uint4*)(wts + OW_O2I0 + i);
    // per-wave bias registers
    float bv0[4], bv1[4], bv2[4], bv3[4], bv4[8];
#pragma unroll
    for (int nt = 0; nt < 4; ++nt) {
        bv0[nt] = b0[nt * 16 + r]; bv1[nt] = b1[nt * 16 + r];
        bv2[nt] = b2[nt * 16 + r]; bv3[nt] = b3[nt * 16 + r];
    }
#pragma unroll
    for (int nt = 0; nt < 8; ++nt) bv4[nt] = b4[nt * 16 + r];
    // zero K-pad cols 144..159 of this wave's rows (once; writeback never touches them)
    unsigned short* Xw = X + (size_t)wv * 32 * 168;
    { const int row = lane >> 1, half = lane & 1;
      *(uint4*)(Xw + row * 168 + 144 + half * 8) = make_uint4(0, 0, 0, 0); }
    const unsigned total = *counter;
    const unsigned nchunks = (total + 31) >> 5;
    __syncthreads();   // weights staged

    for (unsigned c = blockIdx.x * 8 + wv; c < nchunks; c += (unsigned)gridDim.x * 8) {
        const unsigned ebase = c << 5;
        int my_e = -1, my_s = 0, my_d = 0;
        if (lane < 32 && ebase + (unsigned)lane < total) {
            my_e = (int)list[ebase + lane]; my_s = src[my_e]; my_d = dst[my_e];
        }
        // gather 32 edges x 18 8-col chunks
#pragma unroll
        for (int it = 0; it < 9; ++it) {
            const int item = it * 64 + lane;
            const int el = item / 18, q = item - el * 18;
            const int eid = __shfl(my_e, el);
            uint4 pv = make_uint4(0, 0, 0, 0);
            if (eid >= 0) {
                const int sid = __shfl(my_s, el), did = __shfl(my_d, el);
                const float* sp = (q < 8)  ? nf + (size_t)sid * 64 + q * 8
                                : (q < 16) ? nf + (size_t)did * 64 + (q - 8) * 8
                                           : ef + (size_t)eid * 16 + (q - 16) * 8;
                const float4 va = *(const float4*)sp, vb = *(const float4*)(sp + 4);
                pv = make_uint4(pk2(va.x, va.y), pk2(va.z, va.w), pk2(vb.x, vb.y), pk2(vb.z, vb.w));
            }
            *(uint4*)(Xw + el * 168 + q * 8) = pv;
        }
        // 5 layers, no barriers (wave reads only its own rows)
        f32x4 acc[2][4];
        gemm_w<2, 4, 5, 168, 168>(Xw, W + 0,     bv0, lane, acc); writeback_w<2, 4, 168>(Xw, acc, lane);
        gemm_w<2, 4, 2, 168,  72>(Xw, W + 10752, bv1, lane, acc); writeback_w<2, 4, 168>(Xw, acc, lane);
        gemm_w<2, 4, 2, 168,  72>(Xw, W + 15360, bv2, lane, acc); writeback_w<2, 4, 168>(Xw, acc, lane);
        gemm_w<2, 4, 2, 168,  72>(Xw, W + 19968, bv3, lane, acc); writeback_w<2, 4, 168>(Xw, acc, lane);
        f32x4 acc8[2][8];
        gemm_w<2, 8, 2, 168,  72>(Xw, W + 24576, bv4, lane, acc8);
        // scatter-add
#pragma unroll
        for (int mt = 0; mt < 2; ++mt)
#pragma unroll
            for (int q = 0; q < 4; ++q) {
                const int row = mt * 16 + kg * 4 + q;
                const int eid = __shfl(my_e, row);
                if (eid < 0) continue;
                const int did = __shfl(my_d, row);
                float* p = nfi + (size_t)did * 128;
#pragma unroll
                for (int nt = 0; nt < 8; ++nt) atomicAdd(p + nt * 16 + r, acc8[mt][nt][q]);
            }
    }
}

// ---- i2o edge MLP: persistent, barrier-free, gate via shfl ----
__global__ __launch_bounds__(512)
void edge_in_mfma(const float* __restrict__ nf, const float* __restrict__ ef,
                  const int* __restrict__ src, const int* __restrict__ dst,
                  const unsigned* __restrict__ list, const unsigned* __restrict__ counter,
                  const unsigned short* __restrict__ wts,
                  const float* __restrict__ b0, const float* __restrict__ b1,
                  const float* __restrict__ b2, const float* __restrict__ b3,
                  float* __restrict__ f1s, unsigned* __restrict__ f2k, unsigned* __restrict__ cnt) {
    __shared__ unsigned short W[25728];      // all 4 i2o layers
    __shared__ unsigned short X[256 * 168];
    const int tid = threadIdx.x, lane = tid & 63, wv = tid >> 6;
    const int r = lane & 15, kg = lane >> 4;
    for (int i = tid * 8; i < 25728; i += 512 * 8)
        *(uint4*)(W + i) = *(const uint4*)(wts + OW_I2O0 + i);
    float bv0[4], bv1[4], bv2[4], bv3[5];
#pragma unroll
    for (int nt = 0; nt < 4; ++nt) {
        bv0[nt] = b0[nt * 16 + r]; bv1[nt] = b1[nt * 16 + r]; bv2[nt] = b2[nt * 16 + r];
        bv3[nt] = b3[nt * 16 + r];
    }
    bv3[4] = (r == 0) ? b3[64] : 0.0f;
    unsigned short* Xw = X + (size_t)wv * 32 * 168;
    { const int row = lane >> 1, half = lane & 1;
      *(uint4*)(Xw + row * 168 + 144 + half * 8) = make_uint4(0, 0, 0, 0); }
    const unsigned total = *counter;
    const unsigned nchunks = (total + 31) >> 5;
    __syncthreads();

    for (unsigned c = blockIdx.x * 8 + wv; c < nchunks; c += (unsigned)gridDim.x * 8) {
        const unsigned ebase = c << 5;
        int my_e = -1, my_s = 0, my_d = 0;
        if (lane < 32 && ebase + (unsigned)lane < total) {
            my_e = (int)list[ebase + lane]; my_s = src[my_e]; my_d = dst[my_e];
        }
#pragma unroll
        for (int it = 0; it < 9; ++it) {
            const int item = it * 64 + lane;
            const int el = item / 18, q = item - el * 18;
            const int eid = __shfl(my_e, el);
            uint4 pv = make_uint4(0, 0, 0, 0);
            if (eid >= 0) {
                const int sid = __shfl(my_s, el), did = __shfl(my_d, el);
                const float* sp = (q < 8)  ? nf + (size_t)sid * 64 + q * 8
                                : (q < 16) ? nf + (size_t)did * 64 + (q - 8) * 8
                                           : ef + (size_t)eid * 16 + (q - 16) * 8;
                const float4 va = *(const float4*)sp, vb = *(const float4*)(sp + 4);
                pv = make_uint4(pk2(va.x, va.y), pk2(va.z, va.w), pk2(vb.x, vb.y), pk2(vb.z, vb.w));
            }
            *(uint4*)(Xw + el * 168 + q * 8) = pv;
        }
        f32x4 acc[2][4];
        gemm_w<2, 4, 5, 168, 168>(Xw, W + 0,     bv0, lane, acc); writeback_w<2, 4, 168>(Xw, acc, lane);
        gemm_w<2, 4, 2, 168,  72>(Xw, W + 10752, bv1, lane, acc); writeback_w<2, 4, 168>(Xw, acc, lane);
        gemm_w<2, 4, 2, 168,  72>(Xw, W + 15360, bv2, lane, acc); writeback_w<2, 4, 168>(Xw, acc, lane);
        f32x4 acc5[2][5];
        gemm_w<2, 5, 2, 168,  72>(Xw, W + 19968, bv3, lane, acc5);
        // gate + scatter (gate for row mt*16+kg*4+q lives in lane kg*16, elem acc5[mt][4][q])
#pragma unroll
        for (int mt = 0; mt < 2; ++mt)
#pragma unroll
            for (int q = 0; q < 4; ++q) {
                const int row = mt * 16 + kg * 4 + q;
                const int eid = __shfl(my_e, row);
                const float gv = __shfl(acc5[mt][4][q], lane & 48);
                if (eid < 0) continue;
                const int did = __shfl(my_d, row);
                const float kgv = 1.0f / (1.0f + expf(-gv));
                const int rr = did - NOUT_BASE;
#pragma unroll
                for (int nt = 0; nt < 5; ++nt) {
                    const int cc = nt * 16 + r;
                    if (cc == 0 || cc > 64) continue;
                    const float v = acc5[mt][nt][q] * kgv;
                    if (cc <= 32) atomicAdd(f1s + (size_t)rr * 32 + (cc - 1), v);
                    else          atomicMax(f2k + (size_t)rr * 32 + (cc - 33), fkey(v));
                }
                if (r == 0) atomicAdd(cnt + rr, 1u);
            }
    }
}

// ---- ri node MLP (192->64->64->64->64), nodes [0, NIN) ----
__global__ __launch_bounds__(THREADS)
void node_ri_mfma(const float* __restrict__ nf, const float* __restrict__ nfi,
                  const unsigned short* __restrict__ wts,
                  const float* __restrict__ b0, const float* __restrict__ b1,
                  const float* __restrict__ b2, const float* __restrict__ b3,
                  float* __restrict__ out) {
    __shared__ unsigned short X[64 * 200];
    __shared__ unsigned short Wl[12800];
    const int tid = threadIdx.x, lane = tid & 63, wv = tid >> 6;
    const int base = blockIdx.x * 64;
    for (int i = tid; i < 64 * 25; i += THREADS) {
        const int el = i / 25, q = i - el * 25;
        unsigned p0 = 0, p1 = 0, p2 = 0, p3 = 0;
        if (q < 24) {
            const float* sp = (q < 8) ? nf + (size_t)(base + el) * 64 + q * 8
                                      : nfi + (size_t)(base + el) * 128 + (q - 8) * 8;
            const float4 va = *(const float4*)sp, vb = *(const float4*)(sp + 4);
            p0 = pk2(va.x, va.y); p1 = pk2(va.z, va.w); p2 = pk2(vb.x, vb.y); p3 = pk2(vb.z, vb.w);
        }
        *(uint4*)(X + el * 200 + q * 8) = make_uint4(p0, p1, p2, p3);
    }
    auto stage = [&](unsigned off, int n) {
        for (int i = tid * 8; i < n; i += THREADS * 8)
            *(uint4*)(Wl + i) = *(const uint4*)(wts + off + i);
    };
    stage(OW_RI0, 12800);
    __syncthreads();
    f32x4 acc[1][4];
    gemm_core<1, 4, 6, 200, 200>(X, Wl, b0, 64, wv, lane, acc);
    writeback<1, 4, 200>(X, acc, wv, lane);
    __syncthreads(); stage(OW_RI1, 4608); __syncthreads();
    gemm_core<1, 4, 2, 200, 72>(X, Wl, b1, 64, wv, lane, acc);
    writeback<1, 4, 200>(X, acc, wv, lane);
    __syncthreads(); stage(OW_RI2, 4608); __syncthreads();
    gemm_core<1, 4, 2, 200, 72>(X, Wl, b2, 64, wv, lane, acc);
    writeback<1, 4, 200>(X, acc, wv, lane);
    __syncthreads(); stage(OW_RI3, 4608); __syncthreads();
    gemm_core<1, 4, 2, 200, 72>(X, Wl, b3, 64, wv, lane, acc);
    const int r = lane & 15, kg = lane >> 4;
#pragma unroll
    for (int nt = 0; nt < 4; ++nt)
#pragma unroll
        for (int q = 0; q < 4; ++q)
            out[(size_t)(base + wv * 16 + kg * 4 + q) * 64 + nt * 16 + r] = acc[0][nt][q];
}

// ---- ro node MLP (128->64->64->64->64), nodes [NOUT_BASE, N) ----
__global__ __launch_bounds__(THREADS)
void node_ro_mfma(const float* __restrict__ nf, const float* __restrict__ f1s,
                  const unsigned* __restrict__ f2k, const unsigned* __restrict__ cnt,
                  const unsigned short* __restrict__ wts,
                  const float* __restrict__ b0, const float* __restrict__ b1,
                  const float* __restrict__ b2, const float* __restrict__ b3,
                  float* __restrict__ out) {
    __shared__ unsigned short X[64 * 136];
    __shared__ unsigned short Wl[8704];
    const int tid = threadIdx.x, lane = tid & 63, wv = tid >> 6;
    const int rbase = blockIdx.x * 64;
    for (int i = tid; i < 64 * 17; i += THREADS) {
        const int el = i / 17, q = i - el * 17;
        const int rr = rbase + el;
        unsigned p0 = 0, p1 = 0, p2 = 0, p3 = 0;
        if (q < 16) {
            float v[8];
            if (q < 8) {
                const float* sp = nf + (size_t)(NOUT_BASE + rr) * 64 + q * 8;
                const float4 va = *(const float4*)sp, vb = *(const float4*)(sp + 4);
                v[0]=va.x; v[1]=va.y; v[2]=va.z; v[3]=va.w; v[4]=vb.x; v[5]=vb.y; v[6]=vb.z; v[7]=vb.w;
            } else {
                const unsigned cc = cnt[rr];
                if (q < 12) {
                    const float inv = 1.0f / fmaxf((float)cc, 1.0f);
#pragma unroll
                    for (int j = 0; j < 8; ++j) v[j] = f1s[(size_t)rr * 32 + (q - 8) * 8 + j] * inv;
                } else {
#pragma unroll
                    for (int j = 0; j < 8; ++j)
                        v[j] = (cc > 0u) ? funkey(f2k[(size_t)rr * 32 + (q - 12) * 8 + j]) : 0.0f;
                }
            }
            p0 = pk2(v[0], v[1]); p1 = pk2(v[2], v[3]); p2 = pk2(v[4], v[5]); p3 = pk2(v[6], v[7]);
        }
        *(uint4*)(X + el * 136 + q * 8) = make_uint4(p0, p1, p2, p3);
    }
    auto stage = [&](unsigned off, int n) {
        for (int i = tid * 8; i < n; i += THREADS * 8)
            *(uint4*)(Wl + i) = *(const uint4*)(wts + off + i);
    };
    stage(OW_RO0, 8704);
    __syncthreads();
    f32x4 acc[1][4];
    gemm_core<1, 4, 4, 136, 136>(X, Wl, b0, 64, wv, lane, acc);
    writeback<1, 4, 136>(X, acc, wv, lane);
    __syncthreads(); stage(OW_RO1, 4608); __syncthreads();
    gemm_core<1, 4, 2, 136, 72>(X, Wl, b1, 64, wv, lane, acc);
    writeback<1, 4, 136>(X, acc, wv, lane);
    __syncthreads(); stage(OW_RO2, 4608); __syncthreads();
    gemm_core<1, 4, 2, 136, 72>(X, Wl, b2, 64, wv, lane, acc);
    writeback<1, 4, 136>(X, acc, wv, lane);
    __syncthreads(); stage(OW_RO3, 4608); __syncthreads();
    gemm_core<1, 4, 2, 136, 72>(X, Wl, b3, 64, wv, lane, acc);
    const int r = lane & 15, kg = lane >> 4;
#pragma unroll
    for (int nt = 0; nt < 4; ++nt)
#pragma unroll
        for (int q = 0; q < 4; ++q)
            out[(size_t)(NOUT_BASE + rbase + wv * 16 + kg * 4 + q) * 64 + nt * 16 + r] = acc[0][nt][q];
}

extern "C" void kernel_launch(void* const* d_in, const int* in_sizes, int n_in,
                              void* d_out, int out_size, void* d_ws, size_t ws_size,
                              hipStream_t stream) {
    const float* nf     = (const float*)d_in[0];
    const float* ef_out = (const float*)d_in[1];
    const float* ef_in  = (const float*)d_in[2];
    const float* o2i_w[5] = {(const float*)d_in[3], (const float*)d_in[5], (const float*)d_in[7], (const float*)d_in[9], (const float*)d_in[11]};
    const float* o2i_b[5] = {(const float*)d_in[4], (const float*)d_in[6], (const float*)d_in[8], (const float*)d_in[10], (const float*)d_in[12]};
    const float* i2o_w[4] = {(const float*)d_in[13], (const float*)d_in[15], (const float*)d_in[17], (const float*)d_in[19]};
    const float* i2o_b[4] = {(const float*)d_in[14], (const float*)d_in[16], (const float*)d_in[18], (const float*)d_in[20]};
    const float* ri_w[4]  = {(const float*)d_in[21], (const float*)d_in[23], (const float*)d_in[25], (const float*)d_in[27]};
    const float* ri_b[4]  = {(const float*)d_in[22], (const float*)d_in[24], (const float*)d_in[26], (const float*)d_in[28]};
    const float* ro_w[4]  = {(const float*)d_in[29], (const float*)d_in[31], (const float*)d_in[33], (const float*)d_in[35]};
    const float* ro_b[4]  = {(const float*)d_in[30], (const float*)d_in[32], (const float*)d_in[34], (const float*)d_in[36]};
    const int* src_out  = (const int*)d_in[37];
    const int* dst_out  = (const int*)d_in[38];
    const int* src_in   = (const int*)d_in[39];
    const int* dst_in   = (const int*)d_in[40];

    unsigned* ws   = (unsigned*)d_ws;
    float*    nfi  = (float*)(ws + OFF_NFI);
    float*    f1s  = (float*)(ws + OFF_F1);
    unsigned* f2k  = ws + OFF_F2;
    unsigned* cnt  = ws + OFF_CNT;
    unsigned* ctro = ws + OFF_CTRO;
    unsigned* ctri = ws + OFF_CTRI;
    unsigned* lsto = ws + OFF_LISTO;
    unsigned* lsti = ws + OFF_LISTI;
    unsigned short* wts = (unsigned short*)(ws + OFF_WB);
    unsigned* bco  = ws + OFF_BCO;
    unsigned* bci  = ws + OFF_BCI;

    hipMemsetAsync(d_ws, 0, OFF_LISTO * sizeof(unsigned), stream);
    hipMemsetAsync((char*)d_out + (size_t)NIN * 64 * sizeof(float), 0,
                   (size_t)(NOUT_BASE - NIN) * 64 * sizeof(float), stream);

    WTab t;
    t.d[0]  = {o2i_w[0], 144,  64, 168,  64, OW_O2I0};
    t.d[1]  = {o2i_w[1],  64,  64,  72,  64, OW_O2I1};
    t.d[2]  = {o2i_w[2],  64,  64,  72,  64, OW_O2I2};
    t.d[3]  = {o2i_w[3],  64,  64,  72,  64, OW_O2I3};
    t.d[4]  = {o2i_w[4],  64, 128,  72, 128, OW_O2I4};
    t.d[5]  = {i2o_w[0], 144,  64, 168,  64, OW_I2O0};
    t.d[6]  = {i2o_w[1],  64,  64,  72,  64, OW_I2O1};
    t.d[7]  = {i2o_w[2],  64,  64,  72,  64, OW_I2O2};
    t.d[8]  = {i2o_w[3],  64,  65,  72,  80, OW_I2O3};
    t.d[9]  = {ri_w[0],  192,  64, 200,  64, OW_RI0};
    t.d[10] = {ri_w[1],   64,  64,  72,  64, OW_RI1};
    t.d[11] = {ri_w[2],   64,  64,  72,  64, OW_RI2};
    t.d[12] = {ri_w[3],   64,  64,  72,  64, OW_RI3};
    t.d[13] = {ro_w[0],  128,  64, 136,  64, OW_RO0};
    t.d[14] = {ro_w[1],   64,  64,  72,  64, OW_RO1};
    t.d[15] = {ro_w[2],   64,  64,  72,  64, OW_RO2};
    t.d[16] = {ro_w[3],   64,  64,  72,  64, OW_RO3};
    convert_w<<<dim3(50, 17), THREADS, 0, stream>>>(t, wts);

    count_k<<<NBLK, THREADS, 0, stream>>>(dst_out, dst_in, bco, bci);
    scan_k<<<1, 128, 0, stream>>>(bco, bci, ctro, ctri);
    emit_k<<<NBLK, THREADS, 0, stream>>>(dst_out, dst_in, bco, bci, lsto, lsti);

    edge_out_mfma<<<256, 512, 0, stream>>>(
        nf, ef_out, src_out, dst_out, lsto, ctro, wts,
        o2i_b[0], o2i_b[1], o2i_b[2], o2i_b[3], o2i_b[4], nfi);

    edge_in_mfma<<<256, 512, 0, stream>>>(
        nf, ef_in, src_in, dst_in, lsti, ctri, wts,
        i2o_b[0], i2o_b[1], i2o_b[2], i2o_b[3], f1s, f2k, cnt);

    node_ri_mfma<<<NIN / 64, THREADS, 0, stream>>>(
        nf, nfi, wts, ri_b[0], ri_b[1], ri_b[2], ri_b[3], (float*)d_out);

    node_ro_mfma<<<NOUT / 64, THREADS, 0, stream>>>(
        nf, f1s, f2k, cnt, wts, ro_b[0], ro_b[1], ro_b[2], ro_b[3], (float*)d_out);
}

// Round 7
// 391.133 us; speedup vs baseline: 9.3932x; 1.0560x over previous
//
#include <hip/hip_runtime.h>
#include <cmath>

#define THREADS 256

static constexpr int N_NODES   = 100000;
static constexpr int N_EDGES   = 800000;
static constexpr int NIN       = 40000;   // input_mask: n < NIN
static constexpr int NOUT_BASE = 60000;   // output_mask: n >= NOUT_BASE
static constexpr int NOUT      = 40000;

static constexpr int CBLK = 1024;                                  // edges per compaction block
static constexpr int NBLK = (N_EDGES + CBLK - 1) / CBLK;           // 782

// ---- workspace layout (32-bit words) ----
static constexpr size_t OFF_NFI   = 0;                                // 40000*128 f32
static constexpr size_t OFF_F1    = OFF_NFI  + (size_t)NIN  * 128;    // 40000*32  f32
static constexpr size_t OFF_F2    = OFF_F1   + (size_t)NOUT * 32;     // 40000*32  u32 (keys)
static constexpr size_t OFF_CNT   = OFF_F2   + (size_t)NOUT * 32;     // 40000 u32
static constexpr size_t OFF_CTRO  = OFF_CNT  + NOUT;                  // 1 u32
static constexpr size_t OFF_CTRI  = OFF_CTRO + 1;                     // 1 u32
static constexpr size_t OFF_LISTO = OFF_CTRI + 1;                     // E u32
static constexpr size_t OFF_LISTI = OFF_LISTO + N_EDGES;              // E u32
static constexpr size_t OFF_WB    = OFF_LISTI + N_EDGES;              // bf16 weights region (108672 ushorts)
static constexpr size_t OFF_BCO   = OFF_WB + 54336;                   // NBLK u32 block counts/offsets (list O)
static constexpr size_t OFF_BCI   = OFF_BCO + 1024;                   // NBLK u32 (list I)

// converted-weight offsets (ushort units). [n][k] layout, strides = Kp+8 (bank pad)
static constexpr unsigned OW_O2I0 = 0;       // 64 x 168
static constexpr unsigned OW_O2I1 = 10752;   // 64 x 72
static constexpr unsigned OW_O2I2 = 15360;
static constexpr unsigned OW_O2I3 = 19968;
static constexpr unsigned OW_O2I4 = 24576;   // 128 x 72   (o2i total 33792)
static constexpr unsigned OW_I2O0 = 33792;   // 64 x 168
static constexpr unsigned OW_I2O1 = 44544;
static constexpr unsigned OW_I2O2 = 49152;
static constexpr unsigned OW_I2O3 = 53760;   // 80 x 72 (N=65 padded)  (i2o total 25728)
static constexpr unsigned OW_RI0  = 59520;   // 64 x 200
static constexpr unsigned OW_RI1  = 72320;
static constexpr unsigned OW_RI2  = 76928;
static constexpr unsigned OW_RI3  = 81536;
static constexpr unsigned OW_RO0  = 86144;   // 64 x 136
static constexpr unsigned OW_RO1  = 94848;
static constexpr unsigned OW_RO2  = 99456;
static constexpr unsigned OW_RO3  = 104064;  // end 108672

typedef __attribute__((ext_vector_type(8))) short short8;
typedef __attribute__((ext_vector_type(4))) float f32x4;

__device__ __forceinline__ float lrelu(float x) { return x > 0.0f ? x : 0.2f * x; }

__device__ __forceinline__ unsigned short f2b(float f) {   // RNE f32->bf16
    unsigned u = __float_as_uint(f);
    return (unsigned short)((u + 0x7fffu + ((u >> 16) & 1u)) >> 16);
}
__device__ __forceinline__ unsigned pk2(float a, float b) {
    return (unsigned)f2b(a) | ((unsigned)f2b(b) << 16);
}
__device__ __forceinline__ short8 cvt8(const float4 va, const float4 vb) {
    union { uint4 u; short8 s; } t;
    t.u = make_uint4(pk2(va.x, va.y), pk2(va.z, va.w), pk2(vb.x, vb.y), pk2(vb.z, vb.w));
    return t.s;
}
__device__ __forceinline__ unsigned fkey(float f) {
    unsigned u = __float_as_uint(f);
    return (u & 0x80000000u) ? ~u : (u | 0x80000000u);
}
__device__ __forceinline__ float funkey(unsigned k) {
    return (k & 0x80000000u) ? __uint_as_float(k & 0x7fffffffu) : __uint_as_float(~k);
}

// ---- block-cooperative gemm (node kernels) ----
template<int MT, int NT, int KT, int XSTR, int WSTR>
__device__ __forceinline__ void gemm_core(const unsigned short* X, const unsigned short* W,
                                          const float* bias, int biasN, int wv, int lane,
                                          f32x4 (&acc)[MT][NT]) {
    const int r = lane & 15, kg = lane >> 4;
    short8 a[MT][KT];
#pragma unroll
    for (int mt = 0; mt < MT; ++mt)
#pragma unroll
        for (int kk = 0; kk < KT; ++kk)
            a[mt][kk] = *(const short8*)(X + (wv * 16 * MT + mt * 16 + r) * XSTR + kk * 32 + kg * 8);
#pragma unroll
    for (int nt = 0; nt < NT; ++nt) {
        const int c = nt * 16 + r;
        const float bv = (c < biasN) ? bias[c] : 0.0f;
#pragma unroll
        for (int mt = 0; mt < MT; ++mt) acc[mt][nt] = (f32x4){bv, bv, bv, bv};
    }
#pragma unroll
    for (int kk = 0; kk < KT; ++kk)
#pragma unroll
        for (int nt = 0; nt < NT; ++nt) {
            short8 b = *(const short8*)(W + (nt * 16 + r) * WSTR + kk * 32 + kg * 8);
#pragma unroll
            for (int mt = 0; mt < MT; ++mt)
                acc[mt][nt] = __builtin_amdgcn_mfma_f32_16x16x32_bf16(a[mt][kk], b, acc[mt][nt], 0, 0, 0);
        }
}

template<int MT, int NT, int XSTR>
__device__ __forceinline__ void writeback(unsigned short* X, f32x4 (&acc)[MT][NT], int wv, int lane) {
    const int r = lane & 15, kg = lane >> 4;
#pragma unroll
    for (int mt = 0; mt < MT; ++mt)
#pragma unroll
        for (int nt = 0; nt < NT; ++nt)
#pragma unroll
            for (int q = 0; q < 4; ++q)
                X[(wv * 16 * MT + mt * 16 + kg * 4 + q) * XSTR + nt * 16 + r] = f2b(lrelu(acc[mt][nt][q]));
}

// ---- wave-local gemm (edge kernels): Xw = this wave's 16-row region, bias in regs ----
template<int NT, int KT, int XSTR, int WSTR>
__device__ __forceinline__ void gemm_w1(const unsigned short* Xw, const unsigned short* W,
                                        const float* bv, int lane, f32x4 (&acc)[NT]) {
    const int r = lane & 15, kg = lane >> 4;
    short8 a[KT];
#pragma unroll
    for (int kk = 0; kk < KT; ++kk)
        a[kk] = *(const short8*)(Xw + r * XSTR + kk * 32 + kg * 8);
#pragma unroll
    for (int nt = 0; nt < NT; ++nt) acc[nt] = (f32x4){bv[nt], bv[nt], bv[nt], bv[nt]};
#pragma unroll
    for (int kk = 0; kk < KT; ++kk)
#pragma unroll
        for (int nt = 0; nt < NT; ++nt) {
            short8 b = *(const short8*)(W + (nt * 16 + r) * WSTR + kk * 32 + kg * 8);
            acc[nt] = __builtin_amdgcn_mfma_f32_16x16x32_bf16(a[kk], b, acc[nt], 0, 0, 0);
        }
}

template<int NT, int XSTR>
__device__ __forceinline__ void writeback_w1(unsigned short* Xw, f32x4 (&acc)[NT], int lane) {
    const int r = lane & 15, kg = lane >> 4;
#pragma unroll
    for (int nt = 0; nt < NT; ++nt)
#pragma unroll
        for (int q = 0; q < 4; ++q)
            Xw[(kg * 4 + q) * XSTR + nt * 16 + r] = f2b(lrelu(acc[nt][q]));
}

// ---- weight conversion: f32 [K][N] -> bf16 [Np][stride] transposed, zero-padded ----
struct WDesc { const float* w; int K, N, stride, Np; unsigned off; };
struct WTab { WDesc d[17]; };

__global__ __launch_bounds__(THREADS)
void convert_w(WTab t, unsigned short* wts) {
    const WDesc d = t.d[blockIdx.y];
    const int idx = blockIdx.x * THREADS + threadIdx.x;
    const int tot = d.Np * d.stride;
    if (idx >= tot) return;
    const int n = idx / d.stride, k = idx - n * d.stride;
    const float v = (k < d.K && n < d.N) ? d.w[(size_t)k * d.N + n] : 0.0f;
    wts[d.off + idx] = f2b(v);
}

// ---- compaction phase 1: per-block survivor counts ----
__global__ __launch_bounds__(THREADS)
void count_k(const int* __restrict__ dst_out, const int* __restrict__ dst_in,
             unsigned* __restrict__ bco, unsigned* __restrict__ bci) {
    const int base = blockIdx.x * CBLK;
    const int tid = threadIdx.x, lane = tid & 63, wv = tid >> 6;
    __shared__ unsigned so[4], si[4];
    unsigned co = 0, ci = 0;
#pragma unroll
    for (int it = 0; it < CBLK / THREADS; ++it) {
        const int e = base + it * THREADS + tid;
        const bool po = (e < N_EDGES) && (dst_out[e] < NIN);
        const bool pi = (e < N_EDGES) && (dst_in[e] >= NOUT_BASE);
        const unsigned long long mo = __ballot(po), mi = __ballot(pi);
        if (lane == 0) { co += (unsigned)__popcll(mo); ci += (unsigned)__popcll(mi); }
    }
    if (lane == 0) { so[wv] = co; si[wv] = ci; }
    __syncthreads();
    if (tid == 0) {
        bco[blockIdx.x] = so[0] + so[1] + so[2] + so[3];
        bci[blockIdx.x] = si[0] + si[1] + si[2] + si[3];
    }
}

// ---- compaction phase 2: exclusive scan (1 block; wave0=O, wave1=I) ----
__global__ __launch_bounds__(128)
void scan_k(unsigned* __restrict__ bco, unsigned* __restrict__ bci,
            unsigned* __restrict__ ctro, unsigned* __restrict__ ctri) {
    const int lane = threadIdx.x & 63;
    unsigned* arr = (threadIdx.x < 64) ? bco : bci;
    unsigned* tot = (threadIdx.x < 64) ? ctro : ctri;
    const int per = (NBLK + 63) / 64;
    const int lo = lane * per;
    const int hi = (lo + per < NBLK) ? lo + per : NBLK;
    unsigned s = 0;
    for (int i = lo; i < hi; ++i) s += arr[i];
    unsigned incl = s;
    for (int d = 1; d < 64; d <<= 1) {
        unsigned v = __shfl_up(incl, d);
        if (lane >= d) incl += v;
    }
    unsigned run = incl - s;
    for (int i = lo; i < hi; ++i) { const unsigned c = arr[i]; arr[i] = run; run += c; }
    if (lane == 63) *tot = incl;
}

// ---- compaction phase 3: emit survivors ----
__global__ __launch_bounds__(THREADS)
void emit_k(const int* __restrict__ dst_out, const int* __restrict__ dst_in,
            const unsigned* __restrict__ bco, const unsigned* __restrict__ bci,
            unsigned* __restrict__ listo, unsigned* __restrict__ listi) {
    const int base = blockIdx.x * CBLK;
    const int tid = threadIdx.x, lane = tid & 63;
    const unsigned long long lm = (1ull << lane) - 1ull;
    __shared__ unsigned lco, lci;
    if (tid == 0) { lco = bco[blockIdx.x]; lci = bci[blockIdx.x]; }
    __syncthreads();
#pragma unroll
    for (int it = 0; it < CBLK / THREADS; ++it) {
        const int e = base + it * THREADS + tid;
        const bool po = (e < N_EDGES) && (dst_out[e] < NIN);
        const bool pi = (e < N_EDGES) && (dst_in[e] >= NOUT_BASE);
        const unsigned long long mo = __ballot(po), mi = __ballot(pi);
        unsigned bo = 0, bi = 0;
        if (lane == 0) {
            bo = atomicAdd(&lco, (unsigned)__popcll(mo));
            bi = atomicAdd(&lci, (unsigned)__popcll(mi));
        }
        bo = (unsigned)__shfl((int)bo, 0);
        bi = (unsigned)__shfl((int)bi, 0);
        if (po) listo[bo + (unsigned)__popcll(mo & lm)] = (unsigned)e;
        if (pi) listi[bi + (unsigned)__popcll(mi & lm)] = (unsigned)e;
    }
}

// gather layer-0 A-fragments straight into registers (lane r,kg owns row r cols kg*8+kk*32)
__device__ __forceinline__ void gather_a(short8 (&a)[5], const float* nf, const float* ef,
                                         int e16, int s16, int d16, int kg) {
    const short8 z = {0, 0, 0, 0, 0, 0, 0, 0};
    if (e16 >= 0) {
        const float* ps = nf + (size_t)s16 * 64 + kg * 8;
        const float* pd = nf + (size_t)d16 * 64 + kg * 8;
        a[0] = cvt8(((const float4*)ps)[0], ((const float4*)ps)[1]);
        a[1] = cvt8(((const float4*)(ps + 32))[0], ((const float4*)(ps + 32))[1]);
        a[2] = cvt8(((const float4*)pd)[0], ((const float4*)pd)[1]);
        a[3] = cvt8(((const float4*)(pd + 32))[0], ((const float4*)(pd + 32))[1]);
        if (kg < 2) {
            const float* pe = ef + (size_t)e16 * 16 + kg * 8;
            a[4] = cvt8(((const float4*)pe)[0], ((const float4*)pe)[1]);
        } else a[4] = z;
    } else { a[0] = z; a[1] = z; a[2] = z; a[3] = z; a[4] = z; }
}

// ---- o2i edge MLP: 16 edges/wave, reg-gather, layers0-3 LDS, layer4 via L1 ----
__global__ __launch_bounds__(512, 4)
void edge_out_mfma(const float* __restrict__ nf, const float* __restrict__ ef,
                   const int* __restrict__ src, const int* __restrict__ dst,
                   const unsigned* __restrict__ list, const unsigned* __restrict__ counter,
                   const unsigned short* __restrict__ wts,
                   const float* __restrict__ b0, const float* __restrict__ b1,
                   const float* __restrict__ b2, const float* __restrict__ b3,
                   const float* __restrict__ b4, float* __restrict__ nfi) {
    __shared__ unsigned short W[24576];     // layers 0-3 (L0 stride 168, L1-3 stride 72)
    __shared__ unsigned short X[128 * 72];  // 8 waves x 16 rows x 72 (h activations)
    const int tid = threadIdx.x, lane = tid & 63, wv = tid >> 6;
    const int r = lane & 15, kg = lane >> 4;
    for (int i = tid * 8; i < 24576; i += 512 * 8)
        *(uint4*)(W + i) = *(const uint4*)(wts + OW_O2I0 + i);
    float bv0[4], bv1[4], bv2[4], bv3[4], bv4[8];
#pragma unroll
    for (int nt = 0; nt < 4; ++nt) {
        bv0[nt] = b0[nt * 16 + r]; bv1[nt] = b1[nt * 16 + r];
        bv2[nt] = b2[nt * 16 + r]; bv3[nt] = b3[nt * 16 + r];
    }
#pragma unroll
    for (int nt = 0; nt < 8; ++nt) bv4[nt] = b4[nt * 16 + r];
    unsigned short* Xw = X + wv * 16 * 72;
    const unsigned short* W4 = wts + OW_O2I4;   // 18.4KB, L1-resident
    const unsigned total = *counter;
    const unsigned nchunks = (total + 15) >> 4;
    __syncthreads();

    for (unsigned c = blockIdx.x * 8 + wv; c < nchunks; c += (unsigned)gridDim.x * 8) {
        const unsigned ebase = c << 4;
        int my_e = -1, my_s = 0, my_d = 0;
        if (lane < 16 && ebase + (unsigned)lane < total) {
            my_e = (int)list[ebase + lane]; my_s = src[my_e]; my_d = dst[my_e];
        }
        const int e16 = __shfl(my_e, r), s16 = __shfl(my_s, r), d16 = __shfl(my_d, r);
        short8 a[5];
        gather_a(a, nf, ef, e16, s16, d16, kg);
        // layer 0 (K=144+pad, A in regs, B in LDS stride 168)
        f32x4 acc[4];
#pragma unroll
        for (int nt = 0; nt < 4; ++nt) acc[nt] = (f32x4){bv0[nt], bv0[nt], bv0[nt], bv0[nt]};
#pragma unroll
        for (int kk = 0; kk < 5; ++kk)
#pragma unroll
            for (int nt = 0; nt < 4; ++nt) {
                short8 b = *(const short8*)(W + (nt * 16 + r) * 168 + kk * 32 + kg * 8);
                acc[nt] = __builtin_amdgcn_mfma_f32_16x16x32_bf16(a[kk], b, acc[nt], 0, 0, 0);
            }
        writeback_w1<4, 72>(Xw, acc, lane);
        gemm_w1<4, 2, 72, 72>(Xw, W + 10752, bv1, lane, acc); writeback_w1<4, 72>(Xw, acc, lane);
        gemm_w1<4, 2, 72, 72>(Xw, W + 15360, bv2, lane, acc); writeback_w1<4, 72>(Xw, acc, lane);
        gemm_w1<4, 2, 72, 72>(Xw, W + 19968, bv3, lane, acc); writeback_w1<4, 72>(Xw, acc, lane);
        // layer 4 (64 -> 128), B from global (L1-hot)
        short8 a4[2];
#pragma unroll
        for (int kk = 0; kk < 2; ++kk)
            a4[kk] = *(const short8*)(Xw + r * 72 + kk * 32 + kg * 8);
        f32x4 acc8[8];
#pragma unroll
        for (int nt = 0; nt < 8; ++nt) acc8[nt] = (f32x4){bv4[nt], bv4[nt], bv4[nt], bv4[nt]};
#pragma unroll
        for (int kk = 0; kk < 2; ++kk)
#pragma unroll
            for (int nt = 0; nt < 8; ++nt) {
                short8 b = *(const short8*)(W4 + (nt * 16 + r) * 72 + kk * 32 + kg * 8);
                acc8[nt] = __builtin_amdgcn_mfma_f32_16x16x32_bf16(a4[kk], b, acc8[nt], 0, 0, 0);
            }
        // scatter-add
#pragma unroll
        for (int q = 0; q < 4; ++q) {
            const int row = kg * 4 + q;
            const int eid = __shfl(my_e, row);
            if (eid < 0) continue;
            const int did = __shfl(my_d, row);
            float* p = nfi + (size_t)did * 128;
#pragma unroll
            for (int nt = 0; nt < 8; ++nt) atomicAdd(p + nt * 16 + r, acc8[nt][q]);
        }
    }
}

// ---- i2o edge MLP: 16 edges/wave, reg-gather, all weights LDS ----
__global__ __launch_bounds__(512, 4)
void edge_in_mfma(const float* __restrict__ nf, const float* __restrict__ ef,
                  const int* __restrict__ src, const int* __restrict__ dst,
                  const unsigned* __restrict__ list, const unsigned* __restrict__ counter,
                  const unsigned short* __restrict__ wts,
                  const float* __restrict__ b0, const float* __restrict__ b1,
                  const float* __restrict__ b2, const float* __restrict__ b3,
                  float* __restrict__ f1s, unsigned* __restrict__ f2k, unsigned* __restrict__ cnt) {
    __shared__ unsigned short W[25728];     // all 4 i2o layers
    __shared__ unsigned short X[128 * 72];
    const int tid = threadIdx.x, lane = tid & 63, wv = tid >> 6;
    const int r = lane & 15, kg = lane >> 4;
    for (int i = tid * 8; i < 25728; i += 512 * 8)
        *(uint4*)(W + i) = *(const uint4*)(wts + OW_I2O0 + i);
    float bv0[4], bv1[4], bv2[4], bv3[5];
#pragma unroll
    for (int nt = 0; nt < 4; ++nt) {
        bv0[nt] = b0[nt * 16 + r]; bv1[nt] = b1[nt * 16 + r]; bv2[nt] = b2[nt * 16 + r];
        bv3[nt] = b3[nt * 16 + r];
    }
    bv3[4] = (r == 0) ? b3[64] : 0.0f;
    unsigned short* Xw = X + wv * 16 * 72;
    const unsigned total = *counter;
    const unsigned nchunks = (total + 15) >> 4;
    __syncthreads();

    for (unsigned c = blockIdx.x * 8 + wv; c < nchunks; c += (unsigned)gridDim.x * 8) {
        const unsigned ebase = c << 4;
        int my_e = -1, my_s = 0, my_d = 0;
        if (lane < 16 && ebase + (unsigned)lane < total) {
            my_e = (int)list[ebase + lane]; my_s = src[my_e]; my_d = dst[my_e];
        }
        const int e16 = __shfl(my_e, r), s16 = __shfl(my_s, r), d16 = __shfl(my_d, r);
        short8 a[5];
        gather_a(a, nf, ef, e16, s16, d16, kg);
        f32x4 acc[4];
#pragma unroll
        for (int nt = 0; nt < 4; ++nt) acc[nt] = (f32x4){bv0[nt], bv0[nt], bv0[nt], bv0[nt]};
#pragma unroll
        for (int kk = 0; kk < 5; ++kk)
#pragma unroll
            for (int nt = 0; nt < 4; ++nt) {
                short8 b = *(const short8*)(W + (nt * 16 + r) * 168 + kk * 32 + kg * 8);
                acc[nt] = __builtin_amdgcn_mfma_f32_16x16x32_bf16(a[kk], b, acc[nt], 0, 0, 0);
            }
        writeback_w1<4, 72>(Xw, acc, lane);
        gemm_w1<4, 2, 72, 72>(Xw, W + 10752, bv1, lane, acc); writeback_w1<4, 72>(Xw, acc, lane);
        gemm_w1<4, 2, 72, 72>(Xw, W + 15360, bv2, lane, acc); writeback_w1<4, 72>(Xw, acc, lane);
        f32x4 acc5[5];
        gemm_w1<5, 2, 72, 72>(Xw, W + 19968, bv3, lane, acc5);
        // gate + scatter (gate of row kg*4+q held by lane kg*16, elem acc5[4][q])
#pragma unroll
        for (int q = 0; q < 4; ++q) {
            const int row = kg * 4 + q;
            const int eid = __shfl(my_e, row);
            const float gv = __shfl(acc5[4][q], lane & 48);
            if (eid < 0) continue;
            const int did = __shfl(my_d, row);
            const float kgv = 1.0f / (1.0f + expf(-gv));
            const int rr = did - NOUT_BASE;
#pragma unroll
            for (int nt = 0; nt < 5; ++nt) {
                const int cc = nt * 16 + r;
                if (cc == 0 || cc > 64) continue;
                const float v = acc5[nt][q] * kgv;
                if (cc <= 32) atomicAdd(f1s + (size_t)rr * 32 + (cc - 1), v);
                else          atomicMax(f2k + (size_t)rr * 32 + (cc - 33), fkey(v));
            }
            if (r == 0) atomicAdd(cnt + rr, 1u);
        }
    }
}

// ---- ri node MLP (192->64->64->64->64), nodes [0, NIN) ----
__global__ __launch_bounds__(THREADS)
void node_ri_mfma(const float* __restrict__ nf, const float* __restrict__ nfi,
                  const unsigned short* __restrict__ wts,
                  const float* __restrict__ b0, const float* __restrict__ b1,
                  const float* __restrict__ b2, const float* __restrict__ b3,
                  float* __restrict__ out) {
    __shared__ unsigned short X[64 * 200];
    __shared__ unsigned short Wl[12800];
    const int tid = threadIdx.x, lane = tid & 63, wv = tid >> 6;
    const int base = blockIdx.x * 64;
    for (int i = tid; i < 64 * 25; i += THREADS) {
        const int el = i / 25, q = i - el * 25;
        unsigned p0 = 0, p1 = 0, p2 = 0, p3 = 0;
        if (q < 24) {
            const float* sp = (q < 8) ? nf + (size_t)(base + el) * 64 + q * 8
                                      : nfi + (size_t)(base + el) * 128 + (q - 8) * 8;
            const float4 va = *(const float4*)sp, vb = *(const float4*)(sp + 4);
            p0 = pk2(va.x, va.y); p1 = pk2(va.z, va.w); p2 = pk2(vb.x, vb.y); p3 = pk2(vb.z, vb.w);
        }
        *(uint4*)(X + el * 200 + q * 8) = make_uint4(p0, p1, p2, p3);
    }
    auto stage = [&](unsigned off, int n) {
        for (int i = tid * 8; i < n; i += THREADS * 8)
            *(uint4*)(Wl + i) = *(const uint4*)(wts + off + i);
    };
    stage(OW_RI0, 12800);
    __syncthreads();
    f32x4 acc[1][4];
    gemm_core<1, 4, 6, 200, 200>(X, Wl, b0, 64, wv, lane, acc);
    writeback<1, 4, 200>(X, acc, wv, lane);
    __syncthreads(); stage(OW_RI1, 4608); __syncthreads();
    gemm_core<1, 4, 2, 200, 72>(X, Wl, b1, 64, wv, lane, acc);
    writeback<1, 4, 200>(X, acc, wv, lane);
    __syncthreads(); stage(OW_RI2, 4608); __syncthreads();
    gemm_core<1, 4, 2, 200, 72>(X, Wl, b2, 64, wv, lane, acc);
    writeback<1, 4, 200>(X, acc, wv, lane);
    __syncthreads(); stage(OW_RI3, 4608); __syncthreads();
    gemm_core<1, 4, 2, 200, 72>(X, Wl, b3, 64, wv, lane, acc);
    const int r = lane & 15, kg = lane >> 4;
#pragma unroll
    for (int nt = 0; nt < 4; ++nt)
#pragma unroll
        for (int q = 0; q < 4; ++q)
            out[(size_t)(base + wv * 16 + kg * 4 + q) * 64 + nt * 16 + r] = acc[0][nt][q];
}

// ---- ro node MLP (128->64->64->64->64), nodes [NOUT_BASE, N) ----
__global__ __launch_bounds__(THREADS)
void node_ro_mfma(const float* __restrict__ nf, const float* __restrict__ f1s,
                  const unsigned* __restrict__ f2k, const unsigned* __restrict__ cnt,
                  const unsigned short* __restrict__ wts,
                  const float* __restrict__ b0, const float* __restrict__ b1,
                  const float* __restrict__ b2, const float* __restrict__ b3,
                  float* __restrict__ out) {
    __shared__ unsigned short X[64 * 136];
    __shared__ unsigned short Wl[8704];
    const int tid = threadIdx.x, lane = tid & 63, wv = tid >> 6;
    const int rbase = blockIdx.x * 64;
    for (int i = tid; i < 64 * 17; i += THREADS) {
        const int el = i / 17, q = i - el * 17;
        const int rr = rbase + el;
        unsigned p0 = 0, p1 = 0, p2 = 0, p3 = 0;
        if (q < 16) {
            float v[8];
            if (q < 8) {
                const float* sp = nf + (size_t)(NOUT_BASE + rr) * 64 + q * 8;
                const float4 va = *(const float4*)sp, vb = *(const float4*)(sp + 4);
                v[0]=va.x; v[1]=va.y; v[2]=va.z; v[3]=va.w; v[4]=vb.x; v[5]=vb.y; v[6]=vb.z; v[7]=vb.w;
            } else {
                const unsigned cc = cnt[rr];
                if (q < 12) {
                    const float inv = 1.0f / fmaxf((float)cc, 1.0f);
#pragma unroll
                    for (int j = 0; j < 8; ++j) v[j] = f1s[(size_t)rr * 32 + (q - 8) * 8 + j] * inv;
                } else {
#pragma unroll
                    for (int j = 0; j < 8; ++j)
                        v[j] = (cc > 0u) ? funkey(f2k[(size_t)rr * 32 + (q - 12) * 8 + j]) : 0.0f;
                }
            }
            p0 = pk2(v[0], v[1]); p1 = pk2(v[2], v[3]); p2 = pk2(v[4], v[5]); p3 = pk2(v[6], v[7]);
        }
        *(uint4*)(X + el * 136 + q * 8) = make_uint4(p0, p1, p2, p3);
    }
    auto stage = [&](unsigned off, int n) {
        for (int i = tid * 8; i < n; i += THREADS * 8)
            *(uint4*)(Wl + i) = *(const uint4*)(wts + off + i);
    };
    stage(OW_RO0, 8704);
    __syncthreads();
    f32x4 acc[1][4];
    gemm_core<1, 4, 4, 136, 136>(X, Wl, b0, 64, wv, lane, acc);
    writeback<1, 4, 136>(X, acc, wv, lane);
    __syncthreads(); stage(OW_RO1, 4608); __syncthreads();
    gemm_core<1, 4, 2, 136, 72>(X, Wl, b1, 64, wv, lane, acc);
    writeback<1, 4, 136>(X, acc, wv, lane);
    __syncthreads(); stage(OW_RO2, 4608); __syncthreads();
    gemm_core<1, 4, 2, 136, 72>(X, Wl, b2, 64, wv, lane, acc);
    writeback<1, 4, 136>(X, acc, wv, lane);
    __syncthreads(); stage(OW_RO3, 4608); __syncthreads();
    gemm_core<1, 4, 2, 136, 72>(X, Wl, b3, 64, wv, lane, acc);
    const int r = lane & 15, kg = lane >> 4;
#pragma unroll
    for (int nt = 0; nt < 4; ++nt)
#pragma unroll
        for (int q = 0; q < 4; ++q)
            out[(size_t)(NOUT_BASE + rbase + wv * 16 + kg * 4 + q) * 64 + nt * 16 + r] = acc[0][nt][q];
}

extern "C" void kernel_launch(void* const* d_in, const int* in_sizes, int n_in,
                              void* d_out, int out_size, void* d_ws, size_t ws_size,
                              hipStream_t stream) {
    const float* nf     = (const float*)d_in[0];
    const float* ef_out = (const float*)d_in[1];
    const float* ef_in  = (const float*)d_in[2];
    const float* o2i_w[5] = {(const float*)d_in[3], (const float*)d_in[5], (const float*)d_in[7], (const float*)d_in[9], (const float*)d_in[11]};
    const float* o2i_b[5] = {(const float*)d_in[4], (const float*)d_in[6], (const float*)d_in[8], (const float*)d_in[10], (const float*)d_in[12]};
    const float* i2o_w[4] = {(const float*)d_in[13], (const float*)d_in[15], (const float*)d_in[17], (const float*)d_in[19]};
    const float* i2o_b[4] = {(const float*)d_in[14], (const float*)d_in[16], (const float*)d_in[18], (const float*)d_in[20]};
    const float* ri_w[4]  = {(const float*)d_in[21], (const float*)d_in[23], (const float*)d_in[25], (const float*)d_in[27]};
    const float* ri_b[4]  = {(const float*)d_in[22], (const float*)d_in[24], (const float*)d_in[26], (const float*)d_in[28]};
    const float* ro_w[4]  = {(const float*)d_in[29], (const float*)d_in[31], (const float*)d_in[33], (const float*)d_in[35]};
    const float* ro_b[4]  = {(const float*)d_in[30], (const float*)d_in[32], (const float*)d_in[34], (const float*)d_in[36]};
    const int* src_out  = (const int*)d_in[37];
    const int* dst_out  = (const int*)d_in[38];
    const int* src_in   = (const int*)d_in[39];
    const int* dst_in   = (const int*)d_in[40];

    unsigned* ws   = (unsigned*)d_ws;
    float*    nfi  = (float*)(ws + OFF_NFI);
    float*    f1s  = (float*)(ws + OFF_F1);
    unsigned* f2k  = ws + OFF_F2;
    unsigned* cnt  = ws + OFF_CNT;
    unsigned* ctro = ws + OFF_CTRO;
    unsigned* ctri = ws + OFF_CTRI;
    unsigned* lsto = ws + OFF_LISTO;
    unsigned* lsti = ws + OFF_LISTI;
    unsigned short* wts = (unsigned short*)(ws + OFF_WB);
    unsigned* bco  = ws + OFF_BCO;
    unsigned* bci  = ws + OFF_BCI;

    hipMemsetAsync(d_ws, 0, OFF_LISTO * sizeof(unsigned), stream);
    hipMemsetAsync((char*)d_out + (size_t)NIN * 64 * sizeof(float), 0,
                   (size_t)(NOUT_BASE - NIN) * 64 * sizeof(float), stream);

    WTab t;
    t.d[0]  = {o2i_w[0], 144,  64, 168,  64, OW_O2I0};
    t.d[1]  = {o2i_w[1],  64,  64,  72,  64, OW_O2I1};
    t.d[2]  = {o2i_w[2],  64,  64,  72,  64, OW_O2I2};
    t.d[3]  = {o2i_w[3],  64,  64,  72,  64, OW_O2I3};
    t.d[4]  = {o2i_w[4],  64, 128,  72, 128, OW_O2I4};
    t.d[5]  = {i2o_w[0], 144,  64, 168,  64, OW_I2O0};
    t.d[6]  = {i2o_w[1],  64,  64,  72,  64, OW_I2O1};
    t.d[7]  = {i2o_w[2],  64,  64,  72,  64, OW_I2O2};
    t.d[8]  = {i2o_w[3],  64,  65,  72,  80, OW_I2O3};
    t.d[9]  = {ri_w[0],  192,  64, 200,  64, OW_RI0};
    t.d[10] = {ri_w[1],   64,  64,  72,  64, OW_RI1};
    t.d[11] = {ri_w[2],   64,  64,  72,  64, OW_RI2};
    t.d[12] = {ri_w[3],   64,  64,  72,  64, OW_RI3};
    t.d[13] = {ro_w[0],  128,  64, 136,  64, OW_RO0};
    t.d[14] = {ro_w[1],   64,  64,  72,  64, OW_RO1};
    t.d[15] = {ro_w[2],   64,  64,  72,  64, OW_RO2};
    t.d[16] = {ro_w[3],   64,  64,  72,  64, OW_RO3};
    convert_w<<<dim3(50, 17), THREADS, 0, stream>>>(t, wts);

    count_k<<<NBLK, THREADS, 0, stream>>>(dst_out, dst_in, bco, bci);
    scan_k<<<1, 128, 0, stream>>>(bco, bci, ctro, ctri);
    emit_k<<<NBLK, THREADS, 0, stream>>>(dst_out, dst_in, bco, bci, lsto, lsti);

    edge_out_mfma<<<512, 512, 0, stream>>>(
        nf, ef_out, src_out, dst_out, lsto, ctro, wts,
        o2i_b[0], o2i_b[1], o2i_b[2], o2i_b[3], o2i_b[4], nfi);

    edge_in_mfma<<<512, 512, 0, stream>>>(
        nf, ef_in, src_in, dst_in, lsti, ctri, wts,
        i2o_b[0], i2o_b[1], i2o_b[2], i2o_b[3], f1s, f2k, cnt);

    node_ri_mfma<<<NIN / 64, THREADS, 0, stream>>>(
        nf, nfi, wts, ri_b[0], ri_b[1], ri_b[2], ri_b[3], (float*)d_out);

    node_ro_mfma<<<NOUT / 64, THREADS, 0, stream>>>(
        nf, f1s, f2k, cnt, wts, ro_b[0], ro_b[1], ro_b[2], ro_b[3], (float*)d_out);
}